// Round 17
// baseline (232.131 us; speedup 1.0000x reference)
//
#include <hip/hip_runtime.h>
#include <hip/hip_bf16.h>
#include <cstdint>

// Problem constants
#define SEQ   2048
#define DMOD  1024
#define QKVD  2048
#define NH    16
#define HDIM  128
#define NTOK  4096   // B*S

typedef __bf16 bf16;
typedef bf16 bf16x4 __attribute__((ext_vector_type(4)));
typedef bf16 bf16x8 __attribute__((ext_vector_type(8)));
typedef float f32x4 __attribute__((ext_vector_type(4)));
typedef float f32x16 __attribute__((ext_vector_type(16)));
typedef uint32_t u32x4 __attribute__((ext_vector_type(4)));

typedef __attribute__((address_space(1))) void* as1_t;
typedef __attribute__((address_space(3))) void* as3_t;

__device__ __forceinline__ void gload16(const void* g, void* l) {
  __builtin_amdgcn_global_load_lds((as1_t)(uintptr_t)g, (as3_t)(uintptr_t)l, 16, 0, 0);
}

// pack two f32 -> one u32 of 2 bf16
__device__ __forceinline__ uint32_t pkbf(float a, float b) {
  union { bf16 h; unsigned short u; } x, y;
  x.h = (bf16)a; y.h = (bf16)b;
  return (uint32_t)x.u | ((uint32_t)y.u << 16);
}

// v_permlane32_swap_b32: a.lanes[32:63] <-> b.lanes[0:31]
__device__ __forceinline__ void plswap(uint32_t& a, uint32_t& b) {
  asm("v_permlane32_swap_b32 %0, %1" : "+v"(a), "+v"(b));
}

// ---------------- fp32 -> bf16 casts ----------------
__global__ void cast_f32_bf16(const float* __restrict__ in, bf16* __restrict__ out, int n4) {
  int i = blockIdx.x * blockDim.x + threadIdx.x;
  if (i < n4) {
    float4 v = reinterpret_cast<const float4*>(in)[i];
    bf16x4 o;
    o[0] = (bf16)v.x; o[1] = (bf16)v.y; o[2] = (bf16)v.z; o[3] = (bf16)v.w;
    reinterpret_cast<bf16x4*>(out)[i] = o;
  }
}

__global__ void cast_w4(const float* __restrict__ p0, const float* __restrict__ p1,
                        const float* __restrict__ p2, const float* __restrict__ p3,
                        bf16* __restrict__ out) {
  int i = blockIdx.x * blockDim.x + threadIdx.x;   // 0 .. 4*524288
  const float* src = (i < 524288) ? p0 : (i < 1048576) ? p1 : (i < 1572864) ? p2 : p3;
  int off = i & 524287;
  float4 v = reinterpret_cast<const float4*>(src)[off];
  bf16x4 o;
  o[0] = (bf16)v.x; o[1] = (bf16)v.y; o[2] = (bf16)v.z; o[3] = (bf16)v.w;
  reinterpret_cast<bf16x4*>(out)[i] = o;
}

// ---------------- Fused QKV GEMM: 128x256, 3-ring, 4-phase interleave (R8 known-good) ----
__global__ __launch_bounds__(512, 1) void qkv_gemm_kernel(
    const bf16* __restrict__ A, const bf16* __restrict__ Bw,
    bf16* __restrict__ Qo, bf16* __restrict__ Ko, bf16* __restrict__ Vto, float qs)
{
  __shared__ bf16 RING[3][24576];    // per slot: A bytes [0,16384), B bytes [16384,49152)

  const int tid  = threadIdx.x;
  const int lane = tid & 63;
  const int wid  = tid >> 6;     // 0..7
  const int wm   = wid >> 2;     // 0..1
  const int wn   = wid & 3;      // 0..3
  const int lm   = lane & 15;
  const int lg   = lane >> 4;

  // XCD g -> 16 m-blocks x 6 n-panels
  const int g   = blockIdx.x & 7;
  const int idx = blockIdx.x >> 3;           // 0..95
  const int m0  = ((g & 1) * 16 + (idx & 15)) * 128;
  const int n0  = ((g >> 1) * 6 + (idx >> 4)) * 256;

  f32x4 acc[4][4];
#pragma unroll
  for (int i = 0; i < 4; ++i)
#pragma unroll
    for (int j = 0; j < 4; ++j) acc[i][j] = (f32x4)0.0f;

  const int rl = lane >> 3;                  // 0..7
  const int cbb = (lane & 7) * 16;           // byte col base

  auto stageA = [&](int kt, int slot) {      // 2 loads/thread
    const int k0 = kt * 64;
    char* Ab = (char*)&RING[slot][0];
#pragma unroll
    for (int r2 = 0; r2 < 2; ++r2) {
      int chunk = r2 * 8 + wid;              // 0..15
      int row   = chunk * 8 + rl;
      int cx    = cbb ^ ((row & 7) << 4);
      gload16(A + (size_t)(m0 + row) * DMOD + k0 + (cx >> 1), Ab + chunk * 1024);
    }
  };
  auto stageB1 = [&](int kt, int slot, int r2) {  // 1 load/thread
    const int k0 = kt * 64;
    char* Bb = (char*)&RING[slot][0] + 16384;
    int chunk = r2 * 8 + wid;                // 0..31
    int row   = chunk * 8 + rl;
    int cx    = cbb ^ ((row & 7) << 4);
    gload16(Bw + (size_t)(n0 + row) * DMOD + k0 + (cx >> 1), Bb + chunk * 1024);
  };
  auto stageFull = [&](int kt, int slot) {
    stageA(kt, slot);
#pragma unroll
    for (int r2 = 0; r2 < 4; ++r2) stageB1(kt, slot, r2);
  };

  auto rdA = [&](const char* Ab, int mf, int kk) -> bf16x8 {
    int row = wm * 64 + mf * 16 + lm;
    int cx  = (kk * 64 + lg * 16) ^ ((row & 7) << 4);
    return *(const bf16x8*)(Ab + row * 128 + cx);
  };
  auto rdB = [&](const char* Bb, int nf, int kk) -> bf16x8 {
    int row = wn * 64 + nf * 16 + lm;
    int cx  = (kk * 64 + lg * 16) ^ ((row & 7) << 4);
    return *(const bf16x8*)(Bb + row * 128 + cx);
  };

  stageFull(0, 0);
  stageFull(1, 1);

  int cur = 0;
  for (int t = 0; t < 16; ++t) {
    if (t < 15) asm volatile("s_waitcnt vmcnt(6)" ::: "memory");  // tile t landed
    else        asm volatile("s_waitcnt vmcnt(0)" ::: "memory");
    __builtin_amdgcn_s_barrier();

    const char* Ab = (const char*)&RING[cur][0];
    const char* Bb = Ab + 16384;
    const bool pf = (t + 2 < 16);
    const int  ps = (cur + 2 >= 3) ? (cur - 1) : (cur + 2);      // slot of tile t+2

    bf16x8 a[4], b[2];

    // ---- phase 0: mf0-3 x n0-1, kk0 ----
#pragma unroll
    for (int mf = 0; mf < 4; ++mf) a[mf] = rdA(Ab, mf, 0);
    b[0] = rdB(Bb, 0, 0); b[1] = rdB(Bb, 1, 0);
    if (pf) stageA(t + 2, ps);
    __builtin_amdgcn_s_barrier();
    asm volatile("s_waitcnt lgkmcnt(0)" ::: "memory");
    __builtin_amdgcn_s_setprio(1);
#pragma unroll
    for (int mf = 0; mf < 4; ++mf) {
      acc[mf][0] = __builtin_amdgcn_mfma_f32_16x16x32_bf16(a[mf], b[0], acc[mf][0], 0, 0, 0);
      acc[mf][1] = __builtin_amdgcn_mfma_f32_16x16x32_bf16(a[mf], b[1], acc[mf][1], 0, 0, 0);
    }
    __builtin_amdgcn_s_setprio(0);
    __builtin_amdgcn_s_barrier();

    // ---- phase 1: mf0-3 x n2-3, kk0 ----
    b[0] = rdB(Bb, 2, 0); b[1] = rdB(Bb, 3, 0);
    if (pf) { stageB1(t + 2, ps, 0); stageB1(t + 2, ps, 1); }
    __builtin_amdgcn_s_barrier();
    asm volatile("s_waitcnt lgkmcnt(0)" ::: "memory");
    __builtin_amdgcn_s_setprio(1);
#pragma unroll
    for (int mf = 0; mf < 4; ++mf) {
      acc[mf][2] = __builtin_amdgcn_mfma_f32_16x16x32_bf16(a[mf], b[0], acc[mf][2], 0, 0, 0);
      acc[mf][3] = __builtin_amdgcn_mfma_f32_16x16x32_bf16(a[mf], b[1], acc[mf][3], 0, 0, 0);
    }
    __builtin_amdgcn_s_setprio(0);
    __builtin_amdgcn_s_barrier();

    // ---- phase 2: mf0-3 x n0-1, kk1 ----
#pragma unroll
    for (int mf = 0; mf < 4; ++mf) a[mf] = rdA(Ab, mf, 1);
    b[0] = rdB(Bb, 0, 1); b[1] = rdB(Bb, 1, 1);
    if (pf) stageB1(t + 2, ps, 2);
    __builtin_amdgcn_s_barrier();
    asm volatile("s_waitcnt lgkmcnt(0)" ::: "memory");
    __builtin_amdgcn_s_setprio(1);
#pragma unroll
    for (int mf = 0; mf < 4; ++mf) {
      acc[mf][0] = __builtin_amdgcn_mfma_f32_16x16x32_bf16(a[mf], b[0], acc[mf][0], 0, 0, 0);
      acc[mf][1] = __builtin_amdgcn_mfma_f32_16x16x32_bf16(a[mf], b[1], acc[mf][1], 0, 0, 0);
    }
    __builtin_amdgcn_s_setprio(0);
    __builtin_amdgcn_s_barrier();

    // ---- phase 3: mf0-3 x n2-3, kk1 ----
    b[0] = rdB(Bb, 2, 1); b[1] = rdB(Bb, 3, 1);
    if (pf) stageB1(t + 2, ps, 3);
    __builtin_amdgcn_s_barrier();
    asm volatile("s_waitcnt lgkmcnt(0)" ::: "memory");
    __builtin_amdgcn_s_setprio(1);
#pragma unroll
    for (int mf = 0; mf < 4; ++mf) {
      acc[mf][2] = __builtin_amdgcn_mfma_f32_16x16x32_bf16(a[mf], b[0], acc[mf][2], 0, 0, 0);
      acc[mf][3] = __builtin_amdgcn_mfma_f32_16x16x32_bf16(a[mf], b[1], acc[mf][3], 0, 0, 0);
    }
    __builtin_amdgcn_s_setprio(0);
    __builtin_amdgcn_s_barrier();            // iter boundary: tile t consumed by all waves

    cur = (cur == 2) ? 0 : cur + 1;
  }

  // ---- epilogue ----
#pragma unroll
  for (int mf = 0; mf < 4; ++mf) {
#pragma unroll
    for (int nf = 0; nf < 4; ++nf) {
      int row0 = m0 + wm * 64 + mf * 16 + lg * 4;
      int col  = n0 + wn * 64 + nf * 16 + lm;
      f32x4 cv = acc[mf][nf];
      if (n0 < 2048) {
#pragma unroll
        for (int r = 0; r < 4; ++r)
          Qo[(size_t)(row0 + r) * QKVD + col] = (bf16)(cv[r] * qs);
      } else if (n0 < 4096) {
        int kc = col - 2048;
#pragma unroll
        for (int r = 0; r < 4; ++r)
          Ko[(size_t)(row0 + r) * QKVD + kc] = (bf16)cv[r];
      } else {
        int vc = col - 4096;
#pragma unroll
        for (int r = 0; r < 4; ++r) {
          int tok = row0 + r; int bb = tok >> 11; int s = tok & 2047;
          Vto[((size_t)bb * QKVD + vc) * SEQ + s] = (bf16)cv[r];
        }
      }
    }
  }
}

// ---------------- Out-projection: 128x128, ring-2 (2 blocks/CU), 4-phase (R8) ----------------
__global__ __launch_bounds__(256, 2) void proj_kernel(
    const bf16* __restrict__ A, const bf16* __restrict__ Bw, float* __restrict__ out)
{
  __shared__ bf16 RING[2][16384];    // per slot: A [0,16384)B, B [16384,32768)

  const int tid  = threadIdx.x;
  const int lane = tid & 63;
  const int wid  = tid >> 6;     // 0..3
  const int wm   = wid >> 1;
  const int wn   = wid & 1;
  const int lm   = lane & 15;
  const int lg   = lane >> 4;

  // m-major per XCD: XCD g owns m-blocks g*4..g*4+3, all 8 n-panels
  const int g   = blockIdx.x & 7;
  const int idx = blockIdx.x >> 3;           // 0..31
  const int m0  = (g * 4 + (idx >> 3)) * 128;
  const int n0  = (idx & 7) * 128;

  f32x4 acc[4][4];
#pragma unroll
  for (int i = 0; i < 4; ++i)
#pragma unroll
    for (int j = 0; j < 4; ++j) acc[i][j] = (f32x4)0.0f;

  const int rl = lane >> 3;
  const int cbb = (lane & 7) * 16;

  auto stage = [&](int kt, int slot) {       // 8 loads/thread
    const int k0 = kt * 64;
    char* Ab = (char*)&RING[slot][0];
    char* Bb = Ab + 16384;
#pragma unroll
    for (int r2 = 0; r2 < 4; ++r2) {
      int chunk = r2 * 4 + wid;              // 0..15
      int row   = chunk * 8 + rl;
      int cx    = cbb ^ ((row & 7) << 4);
      gload16(A + (size_t)(m0 + row) * QKVD + k0 + (cx >> 1), Ab + chunk * 1024);
    }
#pragma unroll
    for (int r2 = 0; r2 < 4; ++r2) {
      int chunk = r2 * 4 + wid;
      int row   = chunk * 8 + rl;
      int cx    = cbb ^ ((row & 7) << 4);
      gload16(Bw + (size_t)(n0 + row) * QKVD + k0 + (cx >> 1), Bb + chunk * 1024);
    }
  };

  auto rdA = [&](const char* Ab, int mf, int kk) -> bf16x8 {
    int row = wm * 64 + mf * 16 + lm;
    int cx  = (kk * 64 + lg * 16) ^ ((row & 7) << 4);
    return *(const bf16x8*)(Ab + row * 128 + cx);
  };
  auto rdB = [&](const char* Bb, int nf, int kk) -> bf16x8 {
    int row = wn * 64 + nf * 16 + lm;
    int cx  = (kk * 64 + lg * 16) ^ ((row & 7) << 4);
    return *(const bf16x8*)(Bb + row * 128 + cx);
  };

  stage(0, 0);

  int cur = 0;
  for (int t = 0; t < 32; ++t) {
    if (t < 31) {
      stage(t + 1, cur ^ 1);                 // issue BEFORE wait: stays in flight
      asm volatile("s_waitcnt vmcnt(8)" ::: "memory");   // tile t landed
    } else {
      asm volatile("s_waitcnt vmcnt(0)" ::: "memory");
    }
    __builtin_amdgcn_s_barrier();

    const char* Ab = (const char*)&RING[cur][0];
    const char* Bb = Ab + 16384;

    bf16x8 a[4], b[2];

    // ---- phase 0: mf x n0-1 kk0 ----
#pragma unroll
    for (int mf = 0; mf < 4; ++mf) a[mf] = rdA(Ab, mf, 0);
    b[0] = rdB(Bb, 0, 0); b[1] = rdB(Bb, 1, 0);
    __builtin_amdgcn_s_barrier();
    asm volatile("s_waitcnt lgkmcnt(0)" ::: "memory");
    __builtin_amdgcn_s_setprio(1);
#pragma unroll
    for (int mf = 0; mf < 4; ++mf) {
      acc[mf][0] = __builtin_amdgcn_mfma_f32_16x16x32_bf16(a[mf], b[0], acc[mf][0], 0, 0, 0);
      acc[mf][1] = __builtin_amdgcn_mfma_f32_16x16x32_bf16(a[mf], b[1], acc[mf][1], 0, 0, 0);
    }
    __builtin_amdgcn_s_setprio(0);
    __builtin_amdgcn_s_barrier();

    // ---- phase 1: mf x n2-3 kk0 ----
    b[0] = rdB(Bb, 2, 0); b[1] = rdB(Bb, 3, 0);
    __builtin_amdgcn_s_barrier();
    asm volatile("s_waitcnt lgkmcnt(0)" ::: "memory");
    __builtin_amdgcn_s_setprio(1);
#pragma unroll
    for (int mf = 0; mf < 4; ++mf) {
      acc[mf][2] = __builtin_amdgcn_mfma_f32_16x16x32_bf16(a[mf], b[0], acc[mf][2], 0, 0, 0);
      acc[mf][3] = __builtin_amdgcn_mfma_f32_16x16x32_bf16(a[mf], b[1], acc[mf][3], 0, 0, 0);
    }
    __builtin_amdgcn_s_setprio(0);
    __builtin_amdgcn_s_barrier();

    // ---- phase 2: mf x n0-1 kk1 ----
#pragma unroll
    for (int mf = 0; mf < 4; ++mf) a[mf] = rdA(Ab, mf, 1);
    b[0] = rdB(Bb, 0, 1); b[1] = rdB(Bb, 1, 1);
    __builtin_amdgcn_s_barrier();
    asm volatile("s_waitcnt lgkmcnt(0)" ::: "memory");
    __builtin_amdgcn_s_setprio(1);
#pragma unroll
    for (int mf = 0; mf < 4; ++mf) {
      acc[mf][0] = __builtin_amdgcn_mfma_f32_16x16x32_bf16(a[mf], b[0], acc[mf][0], 0, 0, 0);
      acc[mf][1] = __builtin_amdgcn_mfma_f32_16x16x32_bf16(a[mf], b[1], acc[mf][1], 0, 0, 0);
    }
    __builtin_amdgcn_s_setprio(0);
    __builtin_amdgcn_s_barrier();

    // ---- phase 3: mf x n2-3 kk1 ----
    b[0] = rdB(Bb, 2, 1); b[1] = rdB(Bb, 3, 1);
    __builtin_amdgcn_s_barrier();
    asm volatile("s_waitcnt lgkmcnt(0)" ::: "memory");
    __builtin_amdgcn_s_setprio(1);
#pragma unroll
    for (int mf = 0; mf < 4; ++mf) {
      acc[mf][2] = __builtin_amdgcn_mfma_f32_16x16x32_bf16(a[mf], b[0], acc[mf][2], 0, 0, 0);
      acc[mf][3] = __builtin_amdgcn_mfma_f32_16x16x32_bf16(a[mf], b[1], acc[mf][3], 0, 0, 0);
    }
    __builtin_amdgcn_s_setprio(0);
    __builtin_amdgcn_s_barrier();            // iter boundary

    cur ^= 1;
  }

#pragma unroll
  for (int mf = 0; mf < 4; ++mf)
#pragma unroll
    for (int nf = 0; nf < 4; ++nf) {
      int row0 = m0 + wm * 64 + mf * 16 + lg * 4;
      int col  = n0 + wn * 64 + nf * 16 + lm;
      f32x4 cv = acc[mf][nf];
#pragma unroll
      for (int r = 0; r < 4; ++r)
        out[(size_t)(row0 + r) * DMOD + col] = cv[r];
    }
}

// ---------------- Flash attention: 8 waves, key-split wave pairs, LDS merge -------------
// 512 blocks x 512 thr = 4096 waves (4/SIMD at 2 blocks/CU). Waves wg (half=0) and wg+4
// (half=1) process keys [0,32) and [32,64) of each 64-key chunk for q-rows rA..rA+31.
// LDS tile + staging + sync structure identical to R10. Pair-merge via LDS at epilogue.
__global__ __launch_bounds__(512, 4) void flash_kernel(
    const bf16* __restrict__ Q, const bf16* __restrict__ Kg,
    const bf16* __restrict__ Vt, bf16* __restrict__ O)
{
  __shared__ bf16 KV[2][16384];      // per buf: K 64x128 (8192) | Vt 128x64 (8192) = 32KB
  __shared__ float ML[4][64][2];     // (m,l) exchange per pair per lane (2KB)

  const int tid  = threadIdx.x;
  const int lane = tid & 63;
  const int wid  = tid >> 6;         // 0..7
  const int wg   = wid & 3;          // row-group 0..3
  const int half = wid >> 2;         // key half 0/1
  const int l31  = lane & 31;
  const int lh   = lane >> 5;

  const int id  = blockIdx.x;                // 0..511
  const int c   = id & 255;
  const int s   = id >> 8;
  const int bh  = (c & 7) * 4 + ((c >> 3) & 3);
  const int k   = (c >> 5) & 7;
  const int T   = s ? (15 - k) : k;          // tile 0..15
  const int nu  = 2 * (T + 1);               // 64-key chunks
  const int b   = bh >> 4;
  const int h   = bh & 15;
  const int rA  = T * 128 + wg * 32;         // wave's q-row base

  auto stage = [&](int j, int buf) {         // 4 loads/thread (8 waves cooperate)
    bf16* kb = &KV[buf][0];
    bf16* vb = &KV[buf][8192];
    const int rb0 = wid * 8;                 // 8 K-rows per wave
#pragma unroll
    for (int i = 0; i < 2; ++i) {
      int r0 = rb0 + i * 4;
      int r  = r0 + (lane >> 4);
      int cc = ((lane & 15) * 16) ^ ((r & 15) << 4);
      gload16(Kg + ((size_t)(b * SEQ + j * 64 + r)) * QKVD + h * HDIM + (cc >> 1),
              kb + r0 * 128);
    }
    const int db0 = wid * 16;                // 16 V-rows per wave
#pragma unroll
    for (int i = 0; i < 2; ++i) {
      int d0 = db0 + i * 8;
      int d  = d0 + (lane >> 3);
      int cc = ((lane & 7) * 16) ^ ((d & 7) << 4);
      gload16(Vt + ((size_t)(bh * HDIM + d)) * SEQ + j * 64 + (cc >> 1),
              vb + d0 * 64);
    }
  };

  // Q fragments (pre-scaled by SCALE*log2e in GEMM)
  bf16x8 qfr[8];
  {
    const bf16* qb = Q + ((size_t)(b * SEQ + rA + l31)) * QKVD + h * HDIM + lh * 8;
#pragma unroll
    for (int st = 0; st < 8; ++st) qfr[st] = *reinterpret_cast<const bf16x8*>(qb + st * 16);
  }

  f32x16 o[4];
#pragma unroll
  for (int cc = 0; cc < 4; ++cc) o[cc] = (f32x16)0.0f;
  float mreg = -__builtin_inff();
  float lreg = 0.0f;

  stage(0, 0);
  __syncthreads();

  int cur = 0;
  for (int j = 0; j < nu; ++j) {
    if (j + 1 < nu) stage(j + 1, cur ^ 1);   // prefetch; drained by this unit's syncthreads

    const int k0 = j * 64 + half * 32;       // this wave's key base
    const bool act = (k0 <= rA + 31);
    if (act) {
      const char* kbb = (const char*)&KV[cur][0];
      const char* vbb = kbb + 16384;

      // ---- S^T = K Q^T (this wave's 32 keys) ----
      f32x16 s0 = (f32x16)0.0f;
      const int kr = half * 32 + l31;        // K LDS row
#pragma unroll
      for (int st = 0; st < 8; ++st) {
        bf16x8 kf = *(const bf16x8*)(kbb + kr * 256 + ((lh * 16 + st * 32) ^ ((kr & 15) << 4)));
        s0 = __builtin_amdgcn_mfma_f32_32x32x16_bf16(kf, qfr[st], s0, 0, 0, 0);
      }

      // ---- causal mask ----
      const bool full = (k0 + 31) <= rA;
      if (!full) {
        const int qr = rA + l31;
#pragma unroll
        for (int r = 0; r < 16; ++r) {
          int key = k0 + (r & 3) + 8 * (r >> 2) + 4 * lh;
          if (key > qr) s0[r] = -1e30f;
        }
      }

      // ---- row stats ----
      float mx = s0[0];
#pragma unroll
      for (int r = 1; r < 16; ++r) mx = fmaxf(mx, s0[r]);
      mx = fmaxf(mx, __shfl_xor(mx, 32));

      float mn;
      if (__all(mx <= mreg + 8.0f)) {
        mn = mreg;                          // defer-max
      } else {
        mn = fmaxf(mreg, mx);
        float scl = exp2f(mreg - mn);
        mreg = mn;
        lreg *= scl;
#pragma unroll
        for (int r = 0; r < 16; ++r) {
          int row = (r & 3) + 8 * (r >> 2) + 4 * lh;
          float sr = __shfl(scl, row);
#pragma unroll
          for (int cc = 0; cc < 4; ++cc) o[cc][r] *= sr;
        }
      }

      // ---- exp + sum ----
      float p[16];
#pragma unroll
      for (int r = 0; r < 16; ++r) p[r] = exp2f(s0[r] - mn);
      float rs = 0.0f;
#pragma unroll
      for (int r = 0; r < 16; ++r) rs += p[r];
      rs += __shfl_xor(rs, 32);
      lreg += rs;

      // ---- pack P into PV A-fragments (2 frags of 16 keys) ----
      bf16x8 pa[2];
#pragma unroll
      for (int f = 0; f < 2; ++f) {
        const float* pp = p + f * 8;
        uint32_t w0 = pkbf(pp[0], pp[1]);
        uint32_t w1 = pkbf(pp[2], pp[3]);
        uint32_t w2 = pkbf(pp[4], pp[5]);
        uint32_t w3 = pkbf(pp[6], pp[7]);
        plswap(w0, w2);
        plswap(w1, w3);
        u32x4 w = {w0, w1, w2, w3};
        pa[f] = __builtin_bit_cast(bf16x8, w);
      }

      // ---- O += P V (this wave's 32 keys = V byte cols [half*64, half*64+64)) ----
#pragma unroll
      for (int cc = 0; cc < 4; ++cc) {
        const int d = cc * 32 + l31;
        const char* vrow = vbb + d * 128;
        const int dx = (d & 7) << 4;
#pragma unroll
        for (int f = 0; f < 2; ++f) {
          bf16x8 vf = *(const bf16x8*)(vrow + ((half * 64 + f * 32 + lh * 16) ^ dx));
          o[cc] = __builtin_amdgcn_mfma_f32_32x32x16_bf16(pa[f], vf, o[cc], 0, 0, 0);
        }
      }
    }

    __syncthreads();                         // drains prefetch + orders buffer reuse
    cur ^= 1;
  }

  // ---- pair merge via LDS (KV buffers dead; reuse as f32 o-exchange) ----
  float* oex = (float*)&KV[0][0];            // 4 pairs x 64 lanes x 64 f32 = 64KB
  if (half == 1) {
    float* dst = oex + (wg * 64 + lane) * 64;
#pragma unroll
    for (int cc = 0; cc < 4; ++cc)
#pragma unroll
      for (int r = 0; r < 16; ++r) dst[cc * 16 + r] = o[cc][r];
    ML[wg][lane][0] = mreg;
    ML[wg][lane][1] = lreg;
  }
  __syncthreads();

  if (half == 0) {
    float mB = ML[wg][lane][0];
    float lB = ML[wg][lane][1];
    float M  = fmaxf(mreg, mB);
    float wA = exp2f(mreg - M);
    float wB = exp2f(mB - M);
    float linv = 1.0f / (lreg * wA + lB * wB);

    const float* src = oex + (wg * 64 + lane) * 64;
#pragma unroll
    for (int cc = 0; cc < 4; ++cc)
#pragma unroll
      for (int r = 0; r < 16; ++r) {
        int row = (r & 3) + 8 * (r >> 2) + 4 * lh;
        float wAr = __shfl(wA, row);
        float wBr = __shfl(wB, row);
        float lir = __shfl(linv, row);
        float om = (o[cc][r] * wAr + src[cc * 16 + r] * wBr) * lir;
        O[((size_t)(b * SEQ + rA + row)) * QKVD + h * HDIM + cc * 32 + l31] = (bf16)om;
      }
  }
}

// ---------------- launch ----------------
extern "C" void kernel_launch(void* const* d_in, const int* in_sizes, int n_in,
                              void* d_out, int out_size, void* d_ws, size_t ws_size,
                              hipStream_t stream) {
  const float* x  = (const float*)d_in[0];
  const float* wq = (const float*)d_in[1];
  const float* wk = (const float*)d_in[2];
  const float* wv = (const float*)d_in[3];
  const float* wo = (const float*)d_in[4];
  float* out = (float*)d_out;

  bf16* xb  = (bf16*)d_ws;                 // 4096x1024
  bf16* wqb = xb  + (size_t)NTOK * DMOD;   // wq/wk/wv/wo contiguous bf16
  bf16* wob = wqb + (size_t)3 * QKVD * DMOD;
  bf16* Qb  = wob + (size_t)DMOD * QKVD;   // 4096x2048
  bf16* Kb  = Qb  + (size_t)NTOK * QKVD;
  bf16* Vtb = Kb  + (size_t)NTOK * QKVD;
  bf16* Ob  = Vtb + (size_t)NTOK * QKVD;

  // casts
  cast_f32_bf16<<<(NTOK * DMOD / 4) / 256, 256, 0, stream>>>(x, xb, NTOK * DMOD / 4);
  cast_w4<<<8192, 256, 0, stream>>>(wq, wk, wv, wo, wqb);

  // fused QKV projection: [4096,1024] @ [6144,1024]^T, grid 768 (3 exact rounds)
  const float qs = 0.08838834764831845f * 1.4426950408889634f;  // SCALE * log2(e)
  qkv_gemm_kernel<<<768, 512, 0, stream>>>(xb, wqb, Qb, Kb, Vtb, qs);

  // attention: 512 blocks x 512 thr (key-split wave pairs), direct O
  flash_kernel<<<512, 512, 0, stream>>>(Qb, Kb, Vtb, Ob);

  // output projection: [4096,2048] @ [1024,2048]^T -> [4096,1024] fp32, grid 256 (2/CU)
  proj_kernel<<<256, 256, 0, stream>>>(Ob, wob, out);
}

// Round 18
// 176.033 us; speedup vs baseline: 1.3187x; 1.3187x over previous
//
#include <hip/hip_runtime.h>
#include <hip/hip_bf16.h>
#include <cstdint>

// Problem constants
#define SEQ   2048
#define DMOD  1024
#define QKVD  2048
#define NH    16
#define HDIM  128
#define NTOK  4096   // B*S

typedef __bf16 bf16;
typedef bf16 bf16x4 __attribute__((ext_vector_type(4)));
typedef bf16 bf16x8 __attribute__((ext_vector_type(8)));
typedef float f32x4 __attribute__((ext_vector_type(4)));
typedef float f32x16 __attribute__((ext_vector_type(16)));
typedef uint32_t u32x4 __attribute__((ext_vector_type(4)));

typedef __attribute__((address_space(1))) void* as1_t;
typedef __attribute__((address_space(3))) void* as3_t;

__device__ __forceinline__ void gload16(const void* g, void* l) {
  __builtin_amdgcn_global_load_lds((as1_t)(uintptr_t)g, (as3_t)(uintptr_t)l, 16, 0, 0);
}

// pack two f32 -> one u32 of 2 bf16
__device__ __forceinline__ uint32_t pkbf(float a, float b) {
  union { bf16 h; unsigned short u; } x, y;
  x.h = (bf16)a; y.h = (bf16)b;
  return (uint32_t)x.u | ((uint32_t)y.u << 16);
}

// v_permlane32_swap_b32: a.lanes[32:63] <-> b.lanes[0:31]
__device__ __forceinline__ void plswap(uint32_t& a, uint32_t& b) {
  asm("v_permlane32_swap_b32 %0, %1" : "+v"(a), "+v"(b));
}

// ---------------- fp32 -> bf16 cast: x + all 4 weights in ONE launch ----------------
// out layout (bf16): xb [0, 4M) | wq [4M, 6M) | wk | wv | wo  (element counts /1M)
__global__ void cast_all(const float* __restrict__ x,  const float* __restrict__ wq,
                         const float* __restrict__ wk, const float* __restrict__ wv,
                         const float* __restrict__ wo, bf16* __restrict__ out) {
  int i = blockIdx.x * blockDim.x + threadIdx.x;   // 0 .. 3145728 (float4 units)
  const float* src; int off;
  if (i < 1048576)      { src = x;  off = i; }
  else if (i < 1572864) { src = wq; off = i - 1048576; }
  else if (i < 2097152) { src = wk; off = i - 1572864; }
  else if (i < 2621440) { src = wv; off = i - 2097152; }
  else                  { src = wo; off = i - 2621440; }
  float4 v = reinterpret_cast<const float4*>(src)[off];
  bf16x4 o;
  o[0] = (bf16)v.x; o[1] = (bf16)v.y; o[2] = (bf16)v.z; o[3] = (bf16)v.w;
  reinterpret_cast<bf16x4*>(out)[i] = o;
}

// ---------------- Fused QKV GEMM: 128x256, 3-ring, 4-phase interleave (R8 known-good) ----
__global__ __launch_bounds__(512, 1) void qkv_gemm_kernel(
    const bf16* __restrict__ A, const bf16* __restrict__ Bw,
    bf16* __restrict__ Qo, bf16* __restrict__ Ko, bf16* __restrict__ Vto, float qs)
{
  __shared__ bf16 RING[3][24576];    // per slot: A bytes [0,16384), B bytes [16384,49152)

  const int tid  = threadIdx.x;
  const int lane = tid & 63;
  const int wid  = tid >> 6;     // 0..7
  const int wm   = wid >> 2;     // 0..1
  const int wn   = wid & 3;      // 0..3
  const int lm   = lane & 15;
  const int lg   = lane >> 4;

  // XCD g -> 16 m-blocks x 6 n-panels
  const int g   = blockIdx.x & 7;
  const int idx = blockIdx.x >> 3;           // 0..95
  const int m0  = ((g & 1) * 16 + (idx & 15)) * 128;
  const int n0  = ((g >> 1) * 6 + (idx >> 4)) * 256;

  f32x4 acc[4][4];
#pragma unroll
  for (int i = 0; i < 4; ++i)
#pragma unroll
    for (int j = 0; j < 4; ++j) acc[i][j] = (f32x4)0.0f;

  const int rl = lane >> 3;                  // 0..7
  const int cbb = (lane & 7) * 16;           // byte col base

  auto stageA = [&](int kt, int slot) {      // 2 loads/thread
    const int k0 = kt * 64;
    char* Ab = (char*)&RING[slot][0];
#pragma unroll
    for (int r2 = 0; r2 < 2; ++r2) {
      int chunk = r2 * 8 + wid;              // 0..15
      int row   = chunk * 8 + rl;
      int cx    = cbb ^ ((row & 7) << 4);
      gload16(A + (size_t)(m0 + row) * DMOD + k0 + (cx >> 1), Ab + chunk * 1024);
    }
  };
  auto stageB1 = [&](int kt, int slot, int r2) {  // 1 load/thread
    const int k0 = kt * 64;
    char* Bb = (char*)&RING[slot][0] + 16384;
    int chunk = r2 * 8 + wid;                // 0..31
    int row   = chunk * 8 + rl;
    int cx    = cbb ^ ((row & 7) << 4);
    gload16(Bw + (size_t)(n0 + row) * DMOD + k0 + (cx >> 1), Bb + chunk * 1024);
  };
  auto stageFull = [&](int kt, int slot) {
    stageA(kt, slot);
#pragma unroll
    for (int r2 = 0; r2 < 4; ++r2) stageB1(kt, slot, r2);
  };

  auto rdA = [&](const char* Ab, int mf, int kk) -> bf16x8 {
    int row = wm * 64 + mf * 16 + lm;
    int cx  = (kk * 64 + lg * 16) ^ ((row & 7) << 4);
    return *(const bf16x8*)(Ab + row * 128 + cx);
  };
  auto rdB = [&](const char* Bb, int nf, int kk) -> bf16x8 {
    int row = wn * 64 + nf * 16 + lm;
    int cx  = (kk * 64 + lg * 16) ^ ((row & 7) << 4);
    return *(const bf16x8*)(Bb + row * 128 + cx);
  };

  stageFull(0, 0);
  stageFull(1, 1);

  int cur = 0;
  for (int t = 0; t < 16; ++t) {
    if (t < 15) asm volatile("s_waitcnt vmcnt(6)" ::: "memory");  // tile t landed
    else        asm volatile("s_waitcnt vmcnt(0)" ::: "memory");
    __builtin_amdgcn_s_barrier();

    const char* Ab = (const char*)&RING[cur][0];
    const char* Bb = Ab + 16384;
    const bool pf = (t + 2 < 16);
    const int  ps = (cur + 2 >= 3) ? (cur - 1) : (cur + 2);      // slot of tile t+2

    bf16x8 a[4], b[2];

    // ---- phase 0: mf0-3 x n0-1, kk0 ----
#pragma unroll
    for (int mf = 0; mf < 4; ++mf) a[mf] = rdA(Ab, mf, 0);
    b[0] = rdB(Bb, 0, 0); b[1] = rdB(Bb, 1, 0);
    if (pf) stageA(t + 2, ps);
    __builtin_amdgcn_s_barrier();
    asm volatile("s_waitcnt lgkmcnt(0)" ::: "memory");
    __builtin_amdgcn_s_setprio(1);
#pragma unroll
    for (int mf = 0; mf < 4; ++mf) {
      acc[mf][0] = __builtin_amdgcn_mfma_f32_16x16x32_bf16(a[mf], b[0], acc[mf][0], 0, 0, 0);
      acc[mf][1] = __builtin_amdgcn_mfma_f32_16x16x32_bf16(a[mf], b[1], acc[mf][1], 0, 0, 0);
    }
    __builtin_amdgcn_s_setprio(0);
    __builtin_amdgcn_s_barrier();

    // ---- phase 1: mf0-3 x n2-3, kk0 ----
    b[0] = rdB(Bb, 2, 0); b[1] = rdB(Bb, 3, 0);
    if (pf) { stageB1(t + 2, ps, 0); stageB1(t + 2, ps, 1); }
    __builtin_amdgcn_s_barrier();
    asm volatile("s_waitcnt lgkmcnt(0)" ::: "memory");
    __builtin_amdgcn_s_setprio(1);
#pragma unroll
    for (int mf = 0; mf < 4; ++mf) {
      acc[mf][2] = __builtin_amdgcn_mfma_f32_16x16x32_bf16(a[mf], b[0], acc[mf][2], 0, 0, 0);
      acc[mf][3] = __builtin_amdgcn_mfma_f32_16x16x32_bf16(a[mf], b[1], acc[mf][3], 0, 0, 0);
    }
    __builtin_amdgcn_s_setprio(0);
    __builtin_amdgcn_s_barrier();

    // ---- phase 2: mf0-3 x n0-1, kk1 ----
#pragma unroll
    for (int mf = 0; mf < 4; ++mf) a[mf] = rdA(Ab, mf, 1);
    b[0] = rdB(Bb, 0, 1); b[1] = rdB(Bb, 1, 1);
    if (pf) stageB1(t + 2, ps, 2);
    __builtin_amdgcn_s_barrier();
    asm volatile("s_waitcnt lgkmcnt(0)" ::: "memory");
    __builtin_amdgcn_s_setprio(1);
#pragma unroll
    for (int mf = 0; mf < 4; ++mf) {
      acc[mf][0] = __builtin_amdgcn_mfma_f32_16x16x32_bf16(a[mf], b[0], acc[mf][0], 0, 0, 0);
      acc[mf][1] = __builtin_amdgcn_mfma_f32_16x16x32_bf16(a[mf], b[1], acc[mf][1], 0, 0, 0);
    }
    __builtin_amdgcn_s_setprio(0);
    __builtin_amdgcn_s_barrier();

    // ---- phase 3: mf0-3 x n2-3, kk1 ----
    b[0] = rdB(Bb, 2, 1); b[1] = rdB(Bb, 3, 1);
    if (pf) stageB1(t + 2, ps, 3);
    __builtin_amdgcn_s_barrier();
    asm volatile("s_waitcnt lgkmcnt(0)" ::: "memory");
    __builtin_amdgcn_s_setprio(1);
#pragma unroll
    for (int mf = 0; mf < 4; ++mf) {
      acc[mf][2] = __builtin_amdgcn_mfma_f32_16x16x32_bf16(a[mf], b[0], acc[mf][2], 0, 0, 0);
      acc[mf][3] = __builtin_amdgcn_mfma_f32_16x16x32_bf16(a[mf], b[1], acc[mf][3], 0, 0, 0);
    }
    __builtin_amdgcn_s_setprio(0);
    __builtin_amdgcn_s_barrier();            // iter boundary: tile t consumed by all waves

    cur = (cur == 2) ? 0 : cur + 1;
  }

  // ---- epilogue ----
#pragma unroll
  for (int mf = 0; mf < 4; ++mf) {
#pragma unroll
    for (int nf = 0; nf < 4; ++nf) {
      int row0 = m0 + wm * 64 + mf * 16 + lg * 4;
      int col  = n0 + wn * 64 + nf * 16 + lm;
      f32x4 cv = acc[mf][nf];
      if (n0 < 2048) {
#pragma unroll
        for (int r = 0; r < 4; ++r)
          Qo[(size_t)(row0 + r) * QKVD + col] = (bf16)(cv[r] * qs);
      } else if (n0 < 4096) {
        int kc = col - 2048;
#pragma unroll
        for (int r = 0; r < 4; ++r)
          Ko[(size_t)(row0 + r) * QKVD + kc] = (bf16)cv[r];
      } else {
        int vc = col - 4096;
#pragma unroll
        for (int r = 0; r < 4; ++r) {
          int tok = row0 + r; int bb = tok >> 11; int s = tok & 2047;
          Vto[((size_t)bb * QKVD + vc) * SEQ + s] = (bf16)cv[r];
        }
      }
    }
  }
}

// ---------------- Out-projection: 128x128, ring-2, 4-phase (R8) ----------------
__global__ __launch_bounds__(256, 2) void proj_kernel(
    const bf16* __restrict__ A, const bf16* __restrict__ Bw, float* __restrict__ out)
{
  __shared__ bf16 RING[2][16384];    // per slot: A [0,16384)B, B [16384,32768)

  const int tid  = threadIdx.x;
  const int lane = tid & 63;
  const int wid  = tid >> 6;     // 0..3
  const int wm   = wid >> 1;
  const int wn   = wid & 1;
  const int lm   = lane & 15;
  const int lg   = lane >> 4;

  // m-major per XCD: XCD g owns m-blocks g*4..g*4+3, all 8 n-panels
  const int g   = blockIdx.x & 7;
  const int idx = blockIdx.x >> 3;           // 0..31
  const int m0  = (g * 4 + (idx >> 3)) * 128;
  const int n0  = (idx & 7) * 128;

  f32x4 acc[4][4];
#pragma unroll
  for (int i = 0; i < 4; ++i)
#pragma unroll
    for (int j = 0; j < 4; ++j) acc[i][j] = (f32x4)0.0f;

  const int rl = lane >> 3;
  const int cbb = (lane & 7) * 16;

  auto stage = [&](int kt, int slot) {       // 8 loads/thread
    const int k0 = kt * 64;
    char* Ab = (char*)&RING[slot][0];
    char* Bb = Ab + 16384;
#pragma unroll
    for (int r2 = 0; r2 < 4; ++r2) {
      int chunk = r2 * 4 + wid;              // 0..15
      int row   = chunk * 8 + rl;
      int cx    = cbb ^ ((row & 7) << 4);
      gload16(A + (size_t)(m0 + row) * QKVD + k0 + (cx >> 1), Ab + chunk * 1024);
    }
#pragma unroll
    for (int r2 = 0; r2 < 4; ++r2) {
      int chunk = r2 * 4 + wid;
      int row   = chunk * 8 + rl;
      int cx    = cbb ^ ((row & 7) << 4);
      gload16(Bw + (size_t)(n0 + row) * QKVD + k0 + (cx >> 1), Bb + chunk * 1024);
    }
  };

  auto rdA = [&](const char* Ab, int mf, int kk) -> bf16x8 {
    int row = wm * 64 + mf * 16 + lm;
    int cx  = (kk * 64 + lg * 16) ^ ((row & 7) << 4);
    return *(const bf16x8*)(Ab + row * 128 + cx);
  };
  auto rdB = [&](const char* Bb, int nf, int kk) -> bf16x8 {
    int row = wn * 64 + nf * 16 + lm;
    int cx  = (kk * 64 + lg * 16) ^ ((row & 7) << 4);
    return *(const bf16x8*)(Bb + row * 128 + cx);
  };

  stage(0, 0);

  int cur = 0;
  for (int t = 0; t < 32; ++t) {
    if (t < 31) {
      stage(t + 1, cur ^ 1);                 // issue BEFORE wait: stays in flight
      asm volatile("s_waitcnt vmcnt(8)" ::: "memory");   // tile t landed
    } else {
      asm volatile("s_waitcnt vmcnt(0)" ::: "memory");
    }
    __builtin_amdgcn_s_barrier();

    const char* Ab = (const char*)&RING[cur][0];
    const char* Bb = Ab + 16384;

    bf16x8 a[4], b[2];

    // ---- phase 0: mf x n0-1 kk0 ----
#pragma unroll
    for (int mf = 0; mf < 4; ++mf) a[mf] = rdA(Ab, mf, 0);
    b[0] = rdB(Bb, 0, 0); b[1] = rdB(Bb, 1, 0);
    __builtin_amdgcn_s_barrier();
    asm volatile("s_waitcnt lgkmcnt(0)" ::: "memory");
    __builtin_amdgcn_s_setprio(1);
#pragma unroll
    for (int mf = 0; mf < 4; ++mf) {
      acc[mf][0] = __builtin_amdgcn_mfma_f32_16x16x32_bf16(a[mf], b[0], acc[mf][0], 0, 0, 0);
      acc[mf][1] = __builtin_amdgcn_mfma_f32_16x16x32_bf16(a[mf], b[1], acc[mf][1], 0, 0, 0);
    }
    __builtin_amdgcn_s_setprio(0);
    __builtin_amdgcn_s_barrier();

    // ---- phase 1: mf x n2-3 kk0 ----
    b[0] = rdB(Bb, 2, 0); b[1] = rdB(Bb, 3, 0);
    __builtin_amdgcn_s_barrier();
    asm volatile("s_waitcnt lgkmcnt(0)" ::: "memory");
    __builtin_amdgcn_s_setprio(1);
#pragma unroll
    for (int mf = 0; mf < 4; ++mf) {
      acc[mf][2] = __builtin_amdgcn_mfma_f32_16x16x32_bf16(a[mf], b[0], acc[mf][2], 0, 0, 0);
      acc[mf][3] = __builtin_amdgcn_mfma_f32_16x16x32_bf16(a[mf], b[1], acc[mf][3], 0, 0, 0);
    }
    __builtin_amdgcn_s_setprio(0);
    __builtin_amdgcn_s_barrier();

    // ---- phase 2: mf x n0-1 kk1 ----
#pragma unroll
    for (int mf = 0; mf < 4; ++mf) a[mf] = rdA(Ab, mf, 1);
    b[0] = rdB(Bb, 0, 1); b[1] = rdB(Bb, 1, 1);
    __builtin_amdgcn_s_barrier();
    asm volatile("s_waitcnt lgkmcnt(0)" ::: "memory");
    __builtin_amdgcn_s_setprio(1);
#pragma unroll
    for (int mf = 0; mf < 4; ++mf) {
      acc[mf][0] = __builtin_amdgcn_mfma_f32_16x16x32_bf16(a[mf], b[0], acc[mf][0], 0, 0, 0);
      acc[mf][1] = __builtin_amdgcn_mfma_f32_16x16x32_bf16(a[mf], b[1], acc[mf][1], 0, 0, 0);
    }
    __builtin_amdgcn_s_setprio(0);
    __builtin_amdgcn_s_barrier();

    // ---- phase 3: mf x n2-3 kk1 ----
    b[0] = rdB(Bb, 2, 1); b[1] = rdB(Bb, 3, 1);
    __builtin_amdgcn_s_barrier();
    asm volatile("s_waitcnt lgkmcnt(0)" ::: "memory");
    __builtin_amdgcn_s_setprio(1);
#pragma unroll
    for (int mf = 0; mf < 4; ++mf) {
      acc[mf][2] = __builtin_amdgcn_mfma_f32_16x16x32_bf16(a[mf], b[0], acc[mf][2], 0, 0, 0);
      acc[mf][3] = __builtin_amdgcn_mfma_f32_16x16x32_bf16(a[mf], b[1], acc[mf][3], 0, 0, 0);
    }
    __builtin_amdgcn_s_setprio(0);
    __builtin_amdgcn_s_barrier();            // iter boundary

    cur ^= 1;
  }

#pragma unroll
  for (int mf = 0; mf < 4; ++mf)
#pragma unroll
    for (int nf = 0; nf < 4; ++nf) {
      int row0 = m0 + wm * 64 + mf * 16 + lg * 4;
      int col  = n0 + wn * 64 + nf * 16 + lm;
      f32x4 cv = acc[mf][nf];
#pragma unroll
      for (int r = 0; r < 4; ++r)
        out[(size_t)(row0 + r) * DMOD + col] = cv[r];
    }
}

// ---------------- Flash attention: R10 structure + split QK accumulators (R16 best) ----
__global__ __launch_bounds__(256, 2) void flash_kernel(
    const bf16* __restrict__ Q, const bf16* __restrict__ Kg,
    const bf16* __restrict__ Vt, bf16* __restrict__ O)
{
  __shared__ bf16 KV[2][16384];      // per buf: K 64x128 (8192) | Vt 128x64 (8192) = 32KB

  const int tid  = threadIdx.x;
  const int lane = tid & 63;
  const int wid  = tid >> 6;
  const int l31  = lane & 31;
  const int lh   = lane >> 5;        // half: 0/1

  const int id  = blockIdx.x;                // 0..511
  const int c   = id & 255;
  const int s   = id >> 8;                   // CU slot 0/1
  const int bh  = (c & 7) * 4 + ((c >> 3) & 3);  // XCD (c&7) gets 4 bh
  const int k   = (c >> 5) & 7;              // pair index 0..7
  const int T   = s ? (15 - k) : k;          // tile 0..15; i and i+256 complement
  const int nu  = 2 * (T + 1);               // kv-units of 64 keys
  const int b   = bh >> 4;
  const int h   = bh & 15;
  const int rA  = T * 128 + wid * 32;        // wave's q-row base

  auto stage = [&](int j, int buf) {
    bf16* kb = &KV[buf][0];
    bf16* vb = &KV[buf][8192];
    const int rb0 = wid * 16;
#pragma unroll
    for (int i = 0; i < 4; ++i) {
      int r0 = rb0 + i * 4;
      int r  = r0 + (lane >> 4);
      int cc = ((lane & 15) * 16) ^ ((r & 15) << 4);    // full 16-slot swizzle (256B rows)
      gload16(Kg + ((size_t)(b * SEQ + j * 64 + r)) * QKVD + h * HDIM + (cc >> 1),
              kb + r0 * 128);
    }
    const int db0 = wid * 32;
#pragma unroll
    for (int i = 0; i < 4; ++i) {
      int d0 = db0 + i * 8;
      int d  = d0 + (lane >> 3);
      int cc = ((lane & 7) * 16) ^ ((d & 7) << 4);
      gload16(Vt + ((size_t)(bh * HDIM + d)) * SEQ + j * 64 + (cc >> 1),
              vb + d0 * 64);
    }
  };

  // Q fragments (pre-scaled by SCALE*log2e in GEMM)
  bf16x8 qfr[8];
  {
    const bf16* qb = Q + ((size_t)(b * SEQ + rA + l31)) * QKVD + h * HDIM + lh * 8;
#pragma unroll
    for (int st = 0; st < 8; ++st) qfr[st] = *reinterpret_cast<const bf16x8*>(qb + st * 16);
  }

  f32x16 o[4];
#pragma unroll
  for (int cc = 0; cc < 4; ++cc) o[cc] = (f32x16)0.0f;
  float mreg = -__builtin_inff();
  float lreg = 0.0f;

  stage(0, 0);
  __syncthreads();

  int cur = 0;
  for (int j = 0; j < nu; ++j) {
    if (j + 1 < nu) stage(j + 1, cur ^ 1);   // prefetch; drained by this unit's syncthreads

    const bool act = (j * 64 <= rA + 31);
    if (act) {
      const char* kbb = (const char*)&KV[cur][0];
      const char* vbb = kbb + 16384;

      // ---- S^T = K Q^T : 4 independent 4-deep chains ----
      f32x16 s0a = (f32x16)0.0f, s0b = (f32x16)0.0f;
      f32x16 s1a = (f32x16)0.0f, s1b = (f32x16)0.0f;
#pragma unroll
      for (int st = 0; st < 4; ++st) {
        const int r0 = l31, r1 = 32 + l31;
        bf16x8 kf0a = *(const bf16x8*)(kbb + r0 * 256 + ((lh * 16 + st * 32) ^ ((r0 & 15) << 4)));
        bf16x8 kf1a = *(const bf16x8*)(kbb + r1 * 256 + ((lh * 16 + st * 32) ^ ((r1 & 15) << 4)));
        bf16x8 kf0b = *(const bf16x8*)(kbb + r0 * 256 + ((lh * 16 + (st + 4) * 32) ^ ((r0 & 15) << 4)));
        bf16x8 kf1b = *(const bf16x8*)(kbb + r1 * 256 + ((lh * 16 + (st + 4) * 32) ^ ((r1 & 15) << 4)));
        s0a = __builtin_amdgcn_mfma_f32_32x32x16_bf16(kf0a, qfr[st],     s0a, 0, 0, 0);
        s1a = __builtin_amdgcn_mfma_f32_32x32x16_bf16(kf1a, qfr[st],     s1a, 0, 0, 0);
        s0b = __builtin_amdgcn_mfma_f32_32x32x16_bf16(kf0b, qfr[st + 4], s0b, 0, 0, 0);
        s1b = __builtin_amdgcn_mfma_f32_32x32x16_bf16(kf1b, qfr[st + 4], s1b, 0, 0, 0);
      }
      f32x16 s0 = s0a + s0b;
      f32x16 s1 = s1a + s1b;

      // ---- causal mask ----
      const bool full = (j * 64 + 63) <= rA;
      if (!full) {
        const int qr  = rA + l31;
        const int kb0 = j * 64 + 4 * lh;
#pragma unroll
        for (int r = 0; r < 16; ++r) {
          int key = kb0 + (r & 3) + 8 * (r >> 2);
          if (key > qr)      s0[r] = -1e30f;
          if (key + 32 > qr) s1[r] = -1e30f;
        }
      }

      // ---- in-lane row stats ----
      float mx = s0[0];
#pragma unroll
      for (int r = 1; r < 16; ++r) mx = fmaxf(mx, s0[r]);
#pragma unroll
      for (int r = 0; r < 16; ++r) mx = fmaxf(mx, s1[r]);
      mx = fmaxf(mx, __shfl_xor(mx, 32));

      float mn;
      if (__all(mx <= mreg + 8.0f)) {
        mn = mreg;                          // defer-max
      } else {
        mn = fmaxf(mreg, mx);
        float scl = exp2f(mreg - mn);
        mreg = mn;
        lreg *= scl;
#pragma unroll
        for (int r = 0; r < 16; ++r) {
          int row = (r & 3) + 8 * (r >> 2) + 4 * lh;
          float sr = __shfl(scl, row);
#pragma unroll
          for (int cc = 0; cc < 4; ++cc) o[cc][r] *= sr;
        }
      }

      // ---- exp + sum ----
      float p[32];
#pragma unroll
      for (int r = 0; r < 16; ++r) p[r]      = exp2f(s0[r] - mn);
#pragma unroll
      for (int r = 0; r < 16; ++r) p[16 + r] = exp2f(s1[r] - mn);
      float rs = 0.0f;
#pragma unroll
      for (int r = 0; r < 32; ++r) rs += p[r];
      rs += __shfl_xor(rs, 32);
      lreg += rs;

      // ---- pack P into PV A-fragments ----
      bf16x8 pa[4];
#pragma unroll
      for (int f = 0; f < 4; ++f) {
        const float* pp = p + f * 8;
        uint32_t w0 = pkbf(pp[0], pp[1]);
        uint32_t w1 = pkbf(pp[2], pp[3]);
        uint32_t w2 = pkbf(pp[4], pp[5]);
        uint32_t w3 = pkbf(pp[6], pp[7]);
        plswap(w0, w2);
        plswap(w1, w3);
        u32x4 w = {w0, w1, w2, w3};
        pa[f] = __builtin_bit_cast(bf16x8, w);
      }

      // ---- O += P V ----
#pragma unroll
      for (int cc = 0; cc < 4; ++cc) {
        const int d = cc * 32 + l31;
        const char* vrow = vbb + d * 128;
        const int dx = (d & 7) << 4;
#pragma unroll
        for (int f = 0; f < 4; ++f) {
          bf16x8 vf = *(const bf16x8*)(vrow + ((f * 32 + lh * 16) ^ dx));
          o[cc] = __builtin_amdgcn_mfma_f32_32x32x16_bf16(pa[f], vf, o[cc], 0, 0, 0);
        }
      }
    }

    __syncthreads();                         // drains prefetch + orders buffer reuse
    cur ^= 1;
  }

  // ---- epilogue: normalized O, direct write ----
  float linv = 1.0f / lreg;
#pragma unroll
  for (int cc = 0; cc < 4; ++cc)
#pragma unroll
    for (int r = 0; r < 16; ++r) {
      int row = (r & 3) + 8 * (r >> 2) + 4 * lh;
      float li = __shfl(linv, row);        // lane `row` owns q-row (rA+row)'s l
      O[((size_t)(b * SEQ + rA + row)) * QKVD + h * HDIM + cc * 32 + l31] =
          (bf16)(o[cc][r] * li);
    }
}

// ---------------- launch ----------------
extern "C" void kernel_launch(void* const* d_in, const int* in_sizes, int n_in,
                              void* d_out, int out_size, void* d_ws, size_t ws_size,
                              hipStream_t stream) {
  const float* x  = (const float*)d_in[0];
  const float* wq = (const float*)d_in[1];
  const float* wk = (const float*)d_in[2];
  const float* wv = (const float*)d_in[3];
  const float* wo = (const float*)d_in[4];
  float* out = (float*)d_out;

  bf16* xb  = (bf16*)d_ws;                 // 4096x1024
  bf16* wqb = xb  + (size_t)NTOK * DMOD;   // wq/wk/wv/wo contiguous bf16
  bf16* wob = wqb + (size_t)3 * QKVD * DMOD;
  bf16* Qb  = wob + (size_t)DMOD * QKVD;   // 4096x2048
  bf16* Kb  = Qb  + (size_t)NTOK * QKVD;
  bf16* Vtb = Kb  + (size_t)NTOK * QKVD;
  bf16* Ob  = Vtb + (size_t)NTOK * QKVD;

  // single cast launch: x + wq + wk + wv + wo -> bf16 (3145728 float4 units)
  cast_all<<<12288, 256, 0, stream>>>(x, wq, wk, wv, wo, xb);

  // fused QKV projection: [4096,1024] @ [6144,1024]^T, grid 768 (3 exact rounds)
  const float qs = 0.08838834764831845f * 1.4426950408889634f;  // SCALE * log2(e)
  qkv_gemm_kernel<<<768, 512, 0, stream>>>(xb, wqb, Qb, Kb, Vtb, qs);

  // attention: 512 blocks (tile-per-block, complementary CU pairing), direct O
  flash_kernel<<<512, 256, 0, stream>>>(Qb, Kb, Vtb, Ob);

  // output projection: [4096,2048] @ [1024,2048]^T -> [4096,1024] fp32, grid 256
  proj_kernel<<<256, 256, 0, stream>>>(Ob, wob, out);
}

// Round 20
// 175.923 us; speedup vs baseline: 1.3195x; 1.0006x over previous
//
#include <hip/hip_runtime.h>
#include <hip/hip_bf16.h>
#include <cstdint>

// Problem constants
#define SEQ   2048
#define DMOD  1024
#define QKVD  2048
#define NH    16
#define HDIM  128
#define NTOK  4096   // B*S

typedef __bf16 bf16;
typedef bf16 bf16x4 __attribute__((ext_vector_type(4)));
typedef bf16 bf16x8 __attribute__((ext_vector_type(8)));
typedef float f32x4 __attribute__((ext_vector_type(4)));
typedef float f32x16 __attribute__((ext_vector_type(16)));
typedef uint32_t u32x4 __attribute__((ext_vector_type(4)));

typedef __attribute__((address_space(1))) void* as1_t;
typedef __attribute__((address_space(3))) void* as3_t;

__device__ __forceinline__ void gload16(const void* g, void* l) {
  __builtin_amdgcn_global_load_lds((as1_t)(uintptr_t)g, (as3_t)(uintptr_t)l, 16, 0, 0);
}

// pack two f32 -> one u32 of 2 bf16
__device__ __forceinline__ uint32_t pkbf(float a, float b) {
  union { bf16 h; unsigned short u; } x, y;
  x.h = (bf16)a; y.h = (bf16)b;
  return (uint32_t)x.u | ((uint32_t)y.u << 16);
}

// v_permlane32_swap_b32: a.lanes[32:63] <-> b.lanes[0:31]
__device__ __forceinline__ void plswap(uint32_t& a, uint32_t& b) {
  asm("v_permlane32_swap_b32 %0, %1" : "+v"(a), "+v"(b));
}

// ---------------- fp32 -> bf16 cast: x + all 4 weights in ONE launch ----------------
__global__ void cast_all(const float* __restrict__ x,  const float* __restrict__ wq,
                         const float* __restrict__ wk, const float* __restrict__ wv,
                         const float* __restrict__ wo, bf16* __restrict__ out) {
  int i = blockIdx.x * blockDim.x + threadIdx.x;   // 0 .. 3145728 (float4 units)
  const float* src; int off;
  if (i < 1048576)      { src = x;  off = i; }
  else if (i < 1572864) { src = wq; off = i - 1048576; }
  else if (i < 2097152) { src = wk; off = i - 1572864; }
  else if (i < 2621440) { src = wv; off = i - 2097152; }
  else                  { src = wo; off = i - 2621440; }
  float4 v = reinterpret_cast<const float4*>(src)[off];
  bf16x4 o;
  o[0] = (bf16)v.x; o[1] = (bf16)v.y; o[2] = (bf16)v.z; o[3] = (bf16)v.w;
  reinterpret_cast<bf16x4*>(out)[i] = o;
}

// ---------------- Fused QKV GEMM: 128x256, 3-ring, 4-phase interleave (R8 known-good) ----
__global__ __launch_bounds__(512, 1) void qkv_gemm_kernel(
    const bf16* __restrict__ A, const bf16* __restrict__ Bw,
    bf16* __restrict__ Qo, bf16* __restrict__ Ko, bf16* __restrict__ Vto, float qs)
{
  __shared__ bf16 RING[3][24576];    // per slot: A bytes [0,16384), B bytes [16384,49152)

  const int tid  = threadIdx.x;
  const int lane = tid & 63;
  const int wid  = tid >> 6;     // 0..7
  const int wm   = wid >> 2;     // 0..1
  const int wn   = wid & 3;      // 0..3
  const int lm   = lane & 15;
  const int lg   = lane >> 4;

  // XCD g -> 16 m-blocks x 6 n-panels
  const int g   = blockIdx.x & 7;
  const int idx = blockIdx.x >> 3;           // 0..95
  const int m0  = ((g & 1) * 16 + (idx & 15)) * 128;
  const int n0  = ((g >> 1) * 6 + (idx >> 4)) * 256;

  f32x4 acc[4][4];
#pragma unroll
  for (int i = 0; i < 4; ++i)
#pragma unroll
    for (int j = 0; j < 4; ++j) acc[i][j] = (f32x4)0.0f;

  const int rl = lane >> 3;                  // 0..7
  const int cbb = (lane & 7) * 16;           // byte col base

  auto stageA = [&](int kt, int slot) {      // 2 loads/thread
    const int k0 = kt * 64;
    char* Ab = (char*)&RING[slot][0];
#pragma unroll
    for (int r2 = 0; r2 < 2; ++r2) {
      int chunk = r2 * 8 + wid;              // 0..15
      int row   = chunk * 8 + rl;
      int cx    = cbb ^ ((row & 7) << 4);
      gload16(A + (size_t)(m0 + row) * DMOD + k0 + (cx >> 1), Ab + chunk * 1024);
    }
  };
  auto stageB1 = [&](int kt, int slot, int r2) {  // 1 load/thread
    const int k0 = kt * 64;
    char* Bb = (char*)&RING[slot][0] + 16384;
    int chunk = r2 * 8 + wid;                // 0..31
    int row   = chunk * 8 + rl;
    int cx    = cbb ^ ((row & 7) << 4);
    gload16(Bw + (size_t)(n0 + row) * DMOD + k0 + (cx >> 1), Bb + chunk * 1024);
  };
  auto stageFull = [&](int kt, int slot) {
    stageA(kt, slot);
#pragma unroll
    for (int r2 = 0; r2 < 4; ++r2) stageB1(kt, slot, r2);
  };

  auto rdA = [&](const char* Ab, int mf, int kk) -> bf16x8 {
    int row = wm * 64 + mf * 16 + lm;
    int cx  = (kk * 64 + lg * 16) ^ ((row & 7) << 4);
    return *(const bf16x8*)(Ab + row * 128 + cx);
  };
  auto rdB = [&](const char* Bb, int nf, int kk) -> bf16x8 {
    int row = wn * 64 + nf * 16 + lm;
    int cx  = (kk * 64 + lg * 16) ^ ((row & 7) << 4);
    return *(const bf16x8*)(Bb + row * 128 + cx);
  };

  stageFull(0, 0);
  stageFull(1, 1);

  int cur = 0;
  for (int t = 0; t < 16; ++t) {
    if (t < 15) asm volatile("s_waitcnt vmcnt(6)" ::: "memory");  // tile t landed
    else        asm volatile("s_waitcnt vmcnt(0)" ::: "memory");
    __builtin_amdgcn_s_barrier();

    const char* Ab = (const char*)&RING[cur][0];
    const char* Bb = Ab + 16384;
    const bool pf = (t + 2 < 16);
    const int  ps = (cur + 2 >= 3) ? (cur - 1) : (cur + 2);      // slot of tile t+2

    bf16x8 a[4], b[2];

    // ---- phase 0: mf0-3 x n0-1, kk0 ----
#pragma unroll
    for (int mf = 0; mf < 4; ++mf) a[mf] = rdA(Ab, mf, 0);
    b[0] = rdB(Bb, 0, 0); b[1] = rdB(Bb, 1, 0);
    if (pf) stageA(t + 2, ps);
    __builtin_amdgcn_s_barrier();
    asm volatile("s_waitcnt lgkmcnt(0)" ::: "memory");
    __builtin_amdgcn_s_setprio(1);
#pragma unroll
    for (int mf = 0; mf < 4; ++mf) {
      acc[mf][0] = __builtin_amdgcn_mfma_f32_16x16x32_bf16(a[mf], b[0], acc[mf][0], 0, 0, 0);
      acc[mf][1] = __builtin_amdgcn_mfma_f32_16x16x32_bf16(a[mf], b[1], acc[mf][1], 0, 0, 0);
    }
    __builtin_amdgcn_s_setprio(0);
    __builtin_amdgcn_s_barrier();

    // ---- phase 1: mf0-3 x n2-3, kk0 ----
    b[0] = rdB(Bb, 2, 0); b[1] = rdB(Bb, 3, 0);
    if (pf) { stageB1(t + 2, ps, 0); stageB1(t + 2, ps, 1); }
    __builtin_amdgcn_s_barrier();
    asm volatile("s_waitcnt lgkmcnt(0)" ::: "memory");
    __builtin_amdgcn_s_setprio(1);
#pragma unroll
    for (int mf = 0; mf < 4; ++mf) {
      acc[mf][2] = __builtin_amdgcn_mfma_f32_16x16x32_bf16(a[mf], b[0], acc[mf][2], 0, 0, 0);
      acc[mf][3] = __builtin_amdgcn_mfma_f32_16x16x32_bf16(a[mf], b[1], acc[mf][3], 0, 0, 0);
    }
    __builtin_amdgcn_s_setprio(0);
    __builtin_amdgcn_s_barrier();

    // ---- phase 2: mf0-3 x n0-1, kk1 ----
#pragma unroll
    for (int mf = 0; mf < 4; ++mf) a[mf] = rdA(Ab, mf, 1);
    b[0] = rdB(Bb, 0, 1); b[1] = rdB(Bb, 1, 1);
    if (pf) stageB1(t + 2, ps, 2);
    __builtin_amdgcn_s_barrier();
    asm volatile("s_waitcnt lgkmcnt(0)" ::: "memory");
    __builtin_amdgcn_s_setprio(1);
#pragma unroll
    for (int mf = 0; mf < 4; ++mf) {
      acc[mf][0] = __builtin_amdgcn_mfma_f32_16x16x32_bf16(a[mf], b[0], acc[mf][0], 0, 0, 0);
      acc[mf][1] = __builtin_amdgcn_mfma_f32_16x16x32_bf16(a[mf], b[1], acc[mf][1], 0, 0, 0);
    }
    __builtin_amdgcn_s_setprio(0);
    __builtin_amdgcn_s_barrier();

    // ---- phase 3: mf0-3 x n2-3, kk1 ----
    b[0] = rdB(Bb, 2, 1); b[1] = rdB(Bb, 3, 1);
    if (pf) stageB1(t + 2, ps, 3);
    __builtin_amdgcn_s_barrier();
    asm volatile("s_waitcnt lgkmcnt(0)" ::: "memory");
    __builtin_amdgcn_s_setprio(1);
#pragma unroll
    for (int mf = 0; mf < 4; ++mf) {
      acc[mf][2] = __builtin_amdgcn_mfma_f32_16x16x32_bf16(a[mf], b[0], acc[mf][2], 0, 0, 0);
      acc[mf][3] = __builtin_amdgcn_mfma_f32_16x16x32_bf16(a[mf], b[1], acc[mf][3], 0, 0, 0);
    }
    __builtin_amdgcn_s_setprio(0);
    __builtin_amdgcn_s_barrier();            // iter boundary: tile t consumed by all waves

    cur = (cur == 2) ? 0 : cur + 1;
  }

  // ---- epilogue ----
#pragma unroll
  for (int mf = 0; mf < 4; ++mf) {
#pragma unroll
    for (int nf = 0; nf < 4; ++nf) {
      int row0 = m0 + wm * 64 + mf * 16 + lg * 4;
      int col  = n0 + wn * 64 + nf * 16 + lm;
      f32x4 cv = acc[mf][nf];
      if (n0 < 2048) {
#pragma unroll
        for (int r = 0; r < 4; ++r)
          Qo[(size_t)(row0 + r) * QKVD + col] = (bf16)(cv[r] * qs);
      } else if (n0 < 4096) {
        int kc = col - 2048;
#pragma unroll
        for (int r = 0; r < 4; ++r)
          Ko[(size_t)(row0 + r) * QKVD + kc] = (bf16)cv[r];
      } else {
        int vc = col - 4096;
#pragma unroll
        for (int r = 0; r < 4; ++r) {
          int tok = row0 + r; int bb = tok >> 11; int s = tok & 2047;
          Vto[((size_t)bb * QKVD + vc) * SEQ + s] = (bf16)cv[r];
        }
      }
    }
  }
}

// ---------------- Out-projection: 128x128, ring-2, 4-phase (R8) ----------------
__global__ __launch_bounds__(256, 2) void proj_kernel(
    const bf16* __restrict__ A, const bf16* __restrict__ Bw, float* __restrict__ out)
{
  __shared__ bf16 RING[2][16384];    // per slot: A [0,16384)B, B [16384,32768)

  const int tid  = threadIdx.x;
  const int lane = tid & 63;
  const int wid  = tid >> 6;     // 0..3
  const int wm   = wid >> 1;
  const int wn   = wid & 1;
  const int lm   = lane & 15;
  const int lg   = lane >> 4;

  // m-major per XCD: XCD g owns m-blocks g*4..g*4+3, all 8 n-panels
  const int g   = blockIdx.x & 7;
  const int idx = blockIdx.x >> 3;           // 0..31
  const int m0  = (g * 4 + (idx >> 3)) * 128;
  const int n0  = (idx & 7) * 128;

  f32x4 acc[4][4];
#pragma unroll
  for (int i = 0; i < 4; ++i)
#pragma unroll
    for (int j = 0; j < 4; ++j) acc[i][j] = (f32x4)0.0f;

  const int rl = lane >> 3;
  const int cbb = (lane & 7) * 16;

  auto stage = [&](int kt, int slot) {       // 8 loads/thread
    const int k0 = kt * 64;
    char* Ab = (char*)&RING[slot][0];
    char* Bb = Ab + 16384;
#pragma unroll
    for (int r2 = 0; r2 < 4; ++r2) {
      int chunk = r2 * 4 + wid;              // 0..15
      int row   = chunk * 8 + rl;
      int cx    = cbb ^ ((row & 7) << 4);
      gload16(A + (size_t)(m0 + row) * QKVD + k0 + (cx >> 1), Ab + chunk * 1024);
    }
#pragma unroll
    for (int r2 = 0; r2 < 4; ++r2) {
      int chunk = r2 * 4 + wid;
      int row   = chunk * 8 + rl;
      int cx    = cbb ^ ((row & 7) << 4);
      gload16(Bw + (size_t)(n0 + row) * QKVD + k0 + (cx >> 1), Bb + chunk * 1024);
    }
  };

  auto rdA = [&](const char* Ab, int mf, int kk) -> bf16x8 {
    int row = wm * 64 + mf * 16 + lm;
    int cx  = (kk * 64 + lg * 16) ^ ((row & 7) << 4);
    return *(const bf16x8*)(Ab + row * 128 + cx);
  };
  auto rdB = [&](const char* Bb, int nf, int kk) -> bf16x8 {
    int row = wn * 64 + nf * 16 + lm;
    int cx  = (kk * 64 + lg * 16) ^ ((row & 7) << 4);
    return *(const bf16x8*)(Bb + row * 128 + cx);
  };

  stage(0, 0);

  int cur = 0;
  for (int t = 0; t < 32; ++t) {
    if (t < 31) {
      stage(t + 1, cur ^ 1);                 // issue BEFORE wait: stays in flight
      asm volatile("s_waitcnt vmcnt(8)" ::: "memory");   // tile t landed
    } else {
      asm volatile("s_waitcnt vmcnt(0)" ::: "memory");
    }
    __builtin_amdgcn_s_barrier();

    const char* Ab = (const char*)&RING[cur][0];
    const char* Bb = Ab + 16384;

    bf16x8 a[4], b[2];

    // ---- phase 0: mf x n0-1 kk0 ----
#pragma unroll
    for (int mf = 0; mf < 4; ++mf) a[mf] = rdA(Ab, mf, 0);
    b[0] = rdB(Bb, 0, 0); b[1] = rdB(Bb, 1, 0);
    __builtin_amdgcn_s_barrier();
    asm volatile("s_waitcnt lgkmcnt(0)" ::: "memory");
    __builtin_amdgcn_s_setprio(1);
#pragma unroll
    for (int mf = 0; mf < 4; ++mf) {
      acc[mf][0] = __builtin_amdgcn_mfma_f32_16x16x32_bf16(a[mf], b[0], acc[mf][0], 0, 0, 0);
      acc[mf][1] = __builtin_amdgcn_mfma_f32_16x16x32_bf16(a[mf], b[1], acc[mf][1], 0, 0, 0);
    }
    __builtin_amdgcn_s_setprio(0);
    __builtin_amdgcn_s_barrier();

    // ---- phase 1: mf x n2-3 kk0 ----
    b[0] = rdB(Bb, 2, 0); b[1] = rdB(Bb, 3, 0);
    __builtin_amdgcn_s_barrier();
    asm volatile("s_waitcnt lgkmcnt(0)" ::: "memory");
    __builtin_amdgcn_s_setprio(1);
#pragma unroll
    for (int mf = 0; mf < 4; ++mf) {
      acc[mf][2] = __builtin_amdgcn_mfma_f32_16x16x32_bf16(a[mf], b[0], acc[mf][2], 0, 0, 0);
      acc[mf][3] = __builtin_amdgcn_mfma_f32_16x16x32_bf16(a[mf], b[1], acc[mf][3], 0, 0, 0);
    }
    __builtin_amdgcn_s_setprio(0);
    __builtin_amdgcn_s_barrier();

    // ---- phase 2: mf x n0-1 kk1 ----
#pragma unroll
    for (int mf = 0; mf < 4; ++mf) a[mf] = rdA(Ab, mf, 1);
    b[0] = rdB(Bb, 0, 1); b[1] = rdB(Bb, 1, 1);
    __builtin_amdgcn_s_barrier();
    asm volatile("s_waitcnt lgkmcnt(0)" ::: "memory");
    __builtin_amdgcn_s_setprio(1);
#pragma unroll
    for (int mf = 0; mf < 4; ++mf) {
      acc[mf][0] = __builtin_amdgcn_mfma_f32_16x16x32_bf16(a[mf], b[0], acc[mf][0], 0, 0, 0);
      acc[mf][1] = __builtin_amdgcn_mfma_f32_16x16x32_bf16(a[mf], b[1], acc[mf][1], 0, 0, 0);
    }
    __builtin_amdgcn_s_setprio(0);
    __builtin_amdgcn_s_barrier();

    // ---- phase 3: mf x n2-3 kk1 ----
    b[0] = rdB(Bb, 2, 1); b[1] = rdB(Bb, 3, 1);
    __builtin_amdgcn_s_barrier();
    asm volatile("s_waitcnt lgkmcnt(0)" ::: "memory");
    __builtin_amdgcn_s_setprio(1);
#pragma unroll
    for (int mf = 0; mf < 4; ++mf) {
      acc[mf][2] = __builtin_amdgcn_mfma_f32_16x16x32_bf16(a[mf], b[0], acc[mf][2], 0, 0, 0);
      acc[mf][3] = __builtin_amdgcn_mfma_f32_16x16x32_bf16(a[mf], b[1], acc[mf][3], 0, 0, 0);
    }
    __builtin_amdgcn_s_setprio(0);
    __builtin_amdgcn_s_barrier();            // iter boundary

    cur ^= 1;
  }

#pragma unroll
  for (int mf = 0; mf < 4; ++mf)
#pragma unroll
    for (int nf = 0; nf < 4; ++nf) {
      int row0 = m0 + wm * 64 + mf * 16 + lg * 4;
      int col  = n0 + wn * 64 + nf * 16 + lm;
      f32x4 cv = acc[mf][nf];
#pragma unroll
      for (int r = 0; r < 4; ++r)
        out[(size_t)(row0 + r) * DMOD + col] = cv[r];
    }
}

// ---------------- Flash attention: R10 structure + split QK accumulators (R16 best) ----
__global__ __launch_bounds__(256, 2) void flash_kernel(
    const bf16* __restrict__ Q, const bf16* __restrict__ Kg,
    const bf16* __restrict__ Vt, bf16* __restrict__ O)
{
  __shared__ bf16 KV[2][16384];      // per buf: K 64x128 (8192) | Vt 128x64 (8192) = 32KB

  const int tid  = threadIdx.x;
  const int lane = tid & 63;
  const int wid  = tid >> 6;
  const int l31  = lane & 31;
  const int lh   = lane >> 5;        // half: 0/1

  const int id  = blockIdx.x;                // 0..511
  const int c   = id & 255;
  const int s   = id >> 8;                   // CU slot 0/1
  const int bh  = (c & 7) * 4 + ((c >> 3) & 3);  // XCD (c&7) gets 4 bh
  const int k   = (c >> 5) & 7;              // pair index 0..7
  const int T   = s ? (15 - k) : k;          // tile 0..15; i and i+256 complement
  const int nu  = 2 * (T + 1);               // kv-units of 64 keys
  const int b   = bh >> 4;
  const int h   = bh & 15;
  const int rA  = T * 128 + wid * 32;        // wave's q-row base

  auto stage = [&](int j, int buf) {
    bf16* kb = &KV[buf][0];
    bf16* vb = &KV[buf][8192];
    const int rb0 = wid * 16;
#pragma unroll
    for (int i = 0; i < 4; ++i) {
      int r0 = rb0 + i * 4;
      int r  = r0 + (lane >> 4);
      int cc = ((lane & 15) * 16) ^ ((r & 15) << 4);    // full 16-slot swizzle (256B rows)
      gload16(Kg + ((size_t)(b * SEQ + j * 64 + r)) * QKVD + h * HDIM + (cc >> 1),
              kb + r0 * 128);
    }
    const int db0 = wid * 32;
#pragma unroll
    for (int i = 0; i < 4; ++i) {
      int d0 = db0 + i * 8;
      int d  = d0 + (lane >> 3);
      int cc = ((lane & 7) * 16) ^ ((d & 7) << 4);
      gload16(Vt + ((size_t)(bh * HDIM + d)) * SEQ + j * 64 + (cc >> 1),
              vb + d0 * 64);
    }
  };

  // Q fragments (pre-scaled by SCALE*log2e in GEMM)
  bf16x8 qfr[8];
  {
    const bf16* qb = Q + ((size_t)(b * SEQ + rA + l31)) * QKVD + h * HDIM + lh * 8;
#pragma unroll
    for (int st = 0; st < 8; ++st) qfr[st] = *reinterpret_cast<const bf16x8*>(qb + st * 16);
  }

  f32x16 o[4];
#pragma unroll
  for (int cc = 0; cc < 4; ++cc) o[cc] = (f32x16)0.0f;
  float mreg = -__builtin_inff();
  float lreg = 0.0f;

  stage(0, 0);
  __syncthreads();

  int cur = 0;
  for (int j = 0; j < nu; ++j) {
    if (j + 1 < nu) stage(j + 1, cur ^ 1);   // prefetch; drained by this unit's syncthreads

    const bool act = (j * 64 <= rA + 31);
    if (act) {
      const char* kbb = (const char*)&KV[cur][0];
      const char* vbb = kbb + 16384;

      // ---- S^T = K Q^T : 4 independent 4-deep chains ----
      f32x16 s0a = (f32x16)0.0f, s0b = (f32x16)0.0f;
      f32x16 s1a = (f32x16)0.0f, s1b = (f32x16)0.0f;
#pragma unroll
      for (int st = 0; st < 4; ++st) {
        const int r0 = l31, r1 = 32 + l31;
        bf16x8 kf0a = *(const bf16x8*)(kbb + r0 * 256 + ((lh * 16 + st * 32) ^ ((r0 & 15) << 4)));
        bf16x8 kf1a = *(const bf16x8*)(kbb + r1 * 256 + ((lh * 16 + st * 32) ^ ((r1 & 15) << 4)));
        bf16x8 kf0b = *(const bf16x8*)(kbb + r0 * 256 + ((lh * 16 + (st + 4) * 32) ^ ((r0 & 15) << 4)));
        bf16x8 kf1b = *(const bf16x8*)(kbb + r1 * 256 + ((lh * 16 + (st + 4) * 32) ^ ((r1 & 15) << 4)));
        s0a = __builtin_amdgcn_mfma_f32_32x32x16_bf16(kf0a, qfr[st],     s0a, 0, 0, 0);
        s1a = __builtin_amdgcn_mfma_f32_32x32x16_bf16(kf1a, qfr[st],     s1a, 0, 0, 0);
        s0b = __builtin_amdgcn_mfma_f32_32x32x16_bf16(kf0b, qfr[st + 4], s0b, 0, 0, 0);
        s1b = __builtin_amdgcn_mfma_f32_32x32x16_bf16(kf1b, qfr[st + 4], s1b, 0, 0, 0);
      }
      f32x16 s0 = s0a + s0b;
      f32x16 s1 = s1a + s1b;

      // ---- causal mask ----
      const bool full = (j * 64 + 63) <= rA;
      if (!full) {
        const int qr  = rA + l31;
        const int kb0 = j * 64 + 4 * lh;
#pragma unroll
        for (int r = 0; r < 16; ++r) {
          int key = kb0 + (r & 3) + 8 * (r >> 2);
          if (key > qr)      s0[r] = -1e30f;
          if (key + 32 > qr) s1[r] = -1e30f;
        }
      }

      // ---- in-lane row stats ----
      float mx = s0[0];
#pragma unroll
      for (int r = 1; r < 16; ++r) mx = fmaxf(mx, s0[r]);
#pragma unroll
      for (int r = 0; r < 16; ++r) mx = fmaxf(mx, s1[r]);
      mx = fmaxf(mx, __shfl_xor(mx, 32));

      float mn;
      if (__all(mx <= mreg + 8.0f)) {
        mn = mreg;                          // defer-max
      } else {
        mn = fmaxf(mreg, mx);
        float scl = exp2f(mreg - mn);
        mreg = mn;
        lreg *= scl;
#pragma unroll
        for (int r = 0; r < 16; ++r) {
          int row = (r & 3) + 8 * (r >> 2) + 4 * lh;
          float sr = __shfl(scl, row);
#pragma unroll
          for (int cc = 0; cc < 4; ++cc) o[cc][r] *= sr;
        }
      }

      // ---- exp + sum ----
      float p[32];
#pragma unroll
      for (int r = 0; r < 16; ++r) p[r]      = exp2f(s0[r] - mn);
#pragma unroll
      for (int r = 0; r < 16; ++r) p[16 + r] = exp2f(s1[r] - mn);
      float rs = 0.0f;
#pragma unroll
      for (int r = 0; r < 32; ++r) rs += p[r];
      rs += __shfl_xor(rs, 32);
      lreg += rs;

      // ---- pack P into PV A-fragments ----
      bf16x8 pa[4];
#pragma unroll
      for (int f = 0; f < 4; ++f) {
        const float* pp = p + f * 8;
        uint32_t w0 = pkbf(pp[0], pp[1]);
        uint32_t w1 = pkbf(pp[2], pp[3]);
        uint32_t w2 = pkbf(pp[4], pp[5]);
        uint32_t w3 = pkbf(pp[6], pp[7]);
        plswap(w0, w2);
        plswap(w1, w3);
        u32x4 w = {w0, w1, w2, w3};
        pa[f] = __builtin_bit_cast(bf16x8, w);
      }

      // ---- O += P V ----
#pragma unroll
      for (int cc = 0; cc < 4; ++cc) {
        const int d = cc * 32 + l31;
        const char* vrow = vbb + d * 128;
        const int dx = (d & 7) << 4;
#pragma unroll
        for (int f = 0; f < 4; ++f) {
          bf16x8 vf = *(const bf16x8*)(vrow + ((f * 32 + lh * 16) ^ dx));
          o[cc] = __builtin_amdgcn_mfma_f32_32x32x16_bf16(pa[f], vf, o[cc], 0, 0, 0);
        }
      }
    }

    __syncthreads();                         // drains prefetch + orders buffer reuse
    cur ^= 1;
  }

  // ---- epilogue: normalized O, direct write ----
  float linv = 1.0f / lreg;
#pragma unroll
  for (int cc = 0; cc < 4; ++cc)
#pragma unroll
    for (int r = 0; r < 16; ++r) {
      int row = (r & 3) + 8 * (r >> 2) + 4 * lh;
      float li = __shfl(linv, row);        // lane `row` owns q-row (rA+row)'s l
      O[((size_t)(b * SEQ + rA + row)) * QKVD + h * HDIM + cc * 32 + l31] =
          (bf16)(o[cc][r] * li);
    }
}

// ---------------- launch ----------------
extern "C" void kernel_launch(void* const* d_in, const int* in_sizes, int n_in,
                              void* d_out, int out_size, void* d_ws, size_t ws_size,
                              hipStream_t stream) {
  const float* x  = (const float*)d_in[0];
  const float* wq = (const float*)d_in[1];
  const float* wk = (const float*)d_in[2];
  const float* wv = (const float*)d_in[3];
  const float* wo = (const float*)d_in[4];
  float* out = (float*)d_out;

  bf16* xb  = (bf16*)d_ws;                 // 4096x1024
  bf16* wqb = xb  + (size_t)NTOK * DMOD;   // wq/wk/wv/wo contiguous bf16
  bf16* wob = wqb + (size_t)3 * QKVD * DMOD;
  bf16* Qb  = wob + (size_t)DMOD * QKVD;   // 4096x2048
  bf16* Kb  = Qb  + (size_t)NTOK * QKVD;
  bf16* Vtb = Kb  + (size_t)NTOK * QKVD;
  bf16* Ob  = Vtb + (size_t)NTOK * QKVD;

  // single cast launch: x + wq + wk + wv + wo -> bf16 (3145728 float4 units)
  cast_all<<<12288, 256, 0, stream>>>(x, wq, wk, wv, wo, xb);

  // fused QKV projection: [4096,1024] @ [6144,1024]^T, grid 768 (3 exact rounds)
  const float qs = 0.08838834764831845f * 1.4426950408889634f;  // SCALE * log2(e)
  qkv_gemm_kernel<<<768, 512, 0, stream>>>(xb, wqb, Qb, Kb, Vtb, qs);

  // attention: 512 blocks (tile-per-block, complementary CU pairing), direct O
  flash_kernel<<<512, 256, 0, stream>>>(Qb, Kb, Vtb, Ob);

  // output projection: [4096,2048] @ [1024,2048]^T -> [4096,1024] fp32, grid 256
  proj_kernel<<<256, 256, 0, stream>>>(Ob, wob, out);
}

// Round 21
// 171.703 us; speedup vs baseline: 1.3519x; 1.0246x over previous
//
#include <hip/hip_runtime.h>
#include <hip/hip_bf16.h>
#include <cstdint>

// Problem constants
#define SEQ   2048
#define DMOD  1024
#define QKVD  2048
#define NH    16
#define HDIM  128
#define NTOK  4096   // B*S

typedef __bf16 bf16;
typedef bf16 bf16x4 __attribute__((ext_vector_type(4)));
typedef bf16 bf16x8 __attribute__((ext_vector_type(8)));
typedef float f32x4 __attribute__((ext_vector_type(4)));
typedef float f32x16 __attribute__((ext_vector_type(16)));
typedef uint32_t u32x4 __attribute__((ext_vector_type(4)));

typedef __attribute__((address_space(1))) void* as1_t;
typedef __attribute__((address_space(3))) void* as3_t;

__device__ __forceinline__ void gload16(const void* g, void* l) {
  __builtin_amdgcn_global_load_lds((as1_t)(uintptr_t)g, (as3_t)(uintptr_t)l, 16, 0, 0);
}

// pack two f32 -> one u32 of 2 bf16
__device__ __forceinline__ uint32_t pkbf(float a, float b) {
  union { bf16 h; unsigned short u; } x, y;
  x.h = (bf16)a; y.h = (bf16)b;
  return (uint32_t)x.u | ((uint32_t)y.u << 16);
}

// v_permlane32_swap_b32: a.lanes[32:63] <-> b.lanes[0:31]
__device__ __forceinline__ void plswap(uint32_t& a, uint32_t& b) {
  asm("v_permlane32_swap_b32 %0, %1" : "+v"(a), "+v"(b));
}

// ---------------- fp32 -> bf16 cast: x + all 4 weights in ONE launch ----------------
__global__ void cast_all(const float* __restrict__ x,  const float* __restrict__ wq,
                         const float* __restrict__ wk, const float* __restrict__ wv,
                         const float* __restrict__ wo, bf16* __restrict__ out) {
  int i = blockIdx.x * blockDim.x + threadIdx.x;   // 0 .. 3145728 (float4 units)
  const float* src; int off;
  if (i < 1048576)      { src = x;  off = i; }
  else if (i < 1572864) { src = wq; off = i - 1048576; }
  else if (i < 2097152) { src = wk; off = i - 1572864; }
  else if (i < 2621440) { src = wv; off = i - 2097152; }
  else                  { src = wo; off = i - 2621440; }
  float4 v = reinterpret_cast<const float4*>(src)[off];
  bf16x4 o;
  o[0] = (bf16)v.x; o[1] = (bf16)v.y; o[2] = (bf16)v.z; o[3] = (bf16)v.w;
  reinterpret_cast<bf16x4*>(out)[i] = o;
}

// ---------------- Fused QKV GEMM: 128x256, 3-ring, 4-phase interleave (R8 known-good) ----
__global__ __launch_bounds__(512, 1) void qkv_gemm_kernel(
    const bf16* __restrict__ A, const bf16* __restrict__ Bw,
    bf16* __restrict__ Qo, bf16* __restrict__ Ko, bf16* __restrict__ Vto, float qs)
{
  __shared__ bf16 RING[3][24576];    // per slot: A bytes [0,16384), B bytes [16384,49152)

  const int tid  = threadIdx.x;
  const int lane = tid & 63;
  const int wid  = tid >> 6;     // 0..7
  const int wm   = wid >> 2;     // 0..1
  const int wn   = wid & 3;      // 0..3
  const int lm   = lane & 15;
  const int lg   = lane >> 4;

  // XCD g -> 16 m-blocks x 6 n-panels
  const int g   = blockIdx.x & 7;
  const int idx = blockIdx.x >> 3;           // 0..95
  const int m0  = ((g & 1) * 16 + (idx & 15)) * 128;
  const int n0  = ((g >> 1) * 6 + (idx >> 4)) * 256;

  f32x4 acc[4][4];
#pragma unroll
  for (int i = 0; i < 4; ++i)
#pragma unroll
    for (int j = 0; j < 4; ++j) acc[i][j] = (f32x4)0.0f;

  const int rl = lane >> 3;                  // 0..7
  const int cbb = (lane & 7) * 16;           // byte col base

  auto stageA = [&](int kt, int slot) {      // 2 loads/thread
    const int k0 = kt * 64;
    char* Ab = (char*)&RING[slot][0];
#pragma unroll
    for (int r2 = 0; r2 < 2; ++r2) {
      int chunk = r2 * 8 + wid;              // 0..15
      int row   = chunk * 8 + rl;
      int cx    = cbb ^ ((row & 7) << 4);
      gload16(A + (size_t)(m0 + row) * DMOD + k0 + (cx >> 1), Ab + chunk * 1024);
    }
  };
  auto stageB1 = [&](int kt, int slot, int r2) {  // 1 load/thread
    const int k0 = kt * 64;
    char* Bb = (char*)&RING[slot][0] + 16384;
    int chunk = r2 * 8 + wid;                // 0..31
    int row   = chunk * 8 + rl;
    int cx    = cbb ^ ((row & 7) << 4);
    gload16(Bw + (size_t)(n0 + row) * DMOD + k0 + (cx >> 1), Bb + chunk * 1024);
  };
  auto stageFull = [&](int kt, int slot) {
    stageA(kt, slot);
#pragma unroll
    for (int r2 = 0; r2 < 4; ++r2) stageB1(kt, slot, r2);
  };

  auto rdA = [&](const char* Ab, int mf, int kk) -> bf16x8 {
    int row = wm * 64 + mf * 16 + lm;
    int cx  = (kk * 64 + lg * 16) ^ ((row & 7) << 4);
    return *(const bf16x8*)(Ab + row * 128 + cx);
  };
  auto rdB = [&](const char* Bb, int nf, int kk) -> bf16x8 {
    int row = wn * 64 + nf * 16 + lm;
    int cx  = (kk * 64 + lg * 16) ^ ((row & 7) << 4);
    return *(const bf16x8*)(Bb + row * 128 + cx);
  };

  stageFull(0, 0);
  stageFull(1, 1);

  int cur = 0;
  for (int t = 0; t < 16; ++t) {
    if (t < 15) asm volatile("s_waitcnt vmcnt(6)" ::: "memory");  // tile t landed
    else        asm volatile("s_waitcnt vmcnt(0)" ::: "memory");
    __builtin_amdgcn_s_barrier();

    const char* Ab = (const char*)&RING[cur][0];
    const char* Bb = Ab + 16384;
    const bool pf = (t + 2 < 16);
    const int  ps = (cur + 2 >= 3) ? (cur - 1) : (cur + 2);      // slot of tile t+2

    bf16x8 a[4], b[2];

    // ---- phase 0: mf0-3 x n0-1, kk0 ----
#pragma unroll
    for (int mf = 0; mf < 4; ++mf) a[mf] = rdA(Ab, mf, 0);
    b[0] = rdB(Bb, 0, 0); b[1] = rdB(Bb, 1, 0);
    if (pf) stageA(t + 2, ps);
    __builtin_amdgcn_s_barrier();
    asm volatile("s_waitcnt lgkmcnt(0)" ::: "memory");
    __builtin_amdgcn_s_setprio(1);
#pragma unroll
    for (int mf = 0; mf < 4; ++mf) {
      acc[mf][0] = __builtin_amdgcn_mfma_f32_16x16x32_bf16(a[mf], b[0], acc[mf][0], 0, 0, 0);
      acc[mf][1] = __builtin_amdgcn_mfma_f32_16x16x32_bf16(a[mf], b[1], acc[mf][1], 0, 0, 0);
    }
    __builtin_amdgcn_s_setprio(0);
    __builtin_amdgcn_s_barrier();

    // ---- phase 1: mf0-3 x n2-3, kk0 ----
    b[0] = rdB(Bb, 2, 0); b[1] = rdB(Bb, 3, 0);
    if (pf) { stageB1(t + 2, ps, 0); stageB1(t + 2, ps, 1); }
    __builtin_amdgcn_s_barrier();
    asm volatile("s_waitcnt lgkmcnt(0)" ::: "memory");
    __builtin_amdgcn_s_setprio(1);
#pragma unroll
    for (int mf = 0; mf < 4; ++mf) {
      acc[mf][2] = __builtin_amdgcn_mfma_f32_16x16x32_bf16(a[mf], b[0], acc[mf][2], 0, 0, 0);
      acc[mf][3] = __builtin_amdgcn_mfma_f32_16x16x32_bf16(a[mf], b[1], acc[mf][3], 0, 0, 0);
    }
    __builtin_amdgcn_s_setprio(0);
    __builtin_amdgcn_s_barrier();

    // ---- phase 2: mf0-3 x n0-1, kk1 ----
#pragma unroll
    for (int mf = 0; mf < 4; ++mf) a[mf] = rdA(Ab, mf, 1);
    b[0] = rdB(Bb, 0, 1); b[1] = rdB(Bb, 1, 1);
    if (pf) stageB1(t + 2, ps, 2);
    __builtin_amdgcn_s_barrier();
    asm volatile("s_waitcnt lgkmcnt(0)" ::: "memory");
    __builtin_amdgcn_s_setprio(1);
#pragma unroll
    for (int mf = 0; mf < 4; ++mf) {
      acc[mf][0] = __builtin_amdgcn_mfma_f32_16x16x32_bf16(a[mf], b[0], acc[mf][0], 0, 0, 0);
      acc[mf][1] = __builtin_amdgcn_mfma_f32_16x16x32_bf16(a[mf], b[1], acc[mf][1], 0, 0, 0);
    }
    __builtin_amdgcn_s_setprio(0);
    __builtin_amdgcn_s_barrier();

    // ---- phase 3: mf0-3 x n2-3, kk1 ----
    b[0] = rdB(Bb, 2, 1); b[1] = rdB(Bb, 3, 1);
    if (pf) stageB1(t + 2, ps, 3);
    __builtin_amdgcn_s_barrier();
    asm volatile("s_waitcnt lgkmcnt(0)" ::: "memory");
    __builtin_amdgcn_s_setprio(1);
#pragma unroll
    for (int mf = 0; mf < 4; ++mf) {
      acc[mf][2] = __builtin_amdgcn_mfma_f32_16x16x32_bf16(a[mf], b[0], acc[mf][2], 0, 0, 0);
      acc[mf][3] = __builtin_amdgcn_mfma_f32_16x16x32_bf16(a[mf], b[1], acc[mf][3], 0, 0, 0);
    }
    __builtin_amdgcn_s_setprio(0);
    __builtin_amdgcn_s_barrier();            // iter boundary: tile t consumed by all waves

    cur = (cur == 2) ? 0 : cur + 1;
  }

  // ---- epilogue ----
#pragma unroll
  for (int mf = 0; mf < 4; ++mf) {
#pragma unroll
    for (int nf = 0; nf < 4; ++nf) {
      int row0 = m0 + wm * 64 + mf * 16 + lg * 4;
      int col  = n0 + wn * 64 + nf * 16 + lm;
      f32x4 cv = acc[mf][nf];
      if (n0 < 2048) {
#pragma unroll
        for (int r = 0; r < 4; ++r)
          Qo[(size_t)(row0 + r) * QKVD + col] = (bf16)(cv[r] * qs);
      } else if (n0 < 4096) {
        int kc = col - 2048;
#pragma unroll
        for (int r = 0; r < 4; ++r)
          Ko[(size_t)(row0 + r) * QKVD + kc] = (bf16)cv[r];
      } else {
        int vc = col - 4096;
#pragma unroll
        for (int r = 0; r < 4; ++r) {
          int tok = row0 + r; int bb = tok >> 11; int s = tok & 2047;
          Vto[((size_t)bb * QKVD + vc) * SEQ + s] = (bf16)cv[r];
        }
      }
    }
  }
}

// ---------------- Out-projection: 128x64 tile, grid 512 (2 blocks/CU), 2-phase ---------
// out[4096,1024] = Ob[4096,2048] @ wo[1024,2048]^T. 4 waves 2m x 2n, wave tile 64x32.
// 32 K-tiles of 64. LDS dbuf 2 x (A 16KB + B 8KB) = 48KB. Counted vmcnt(6).
__global__ __launch_bounds__(256, 2) void proj_kernel(
    const bf16* __restrict__ A, const bf16* __restrict__ Bw, float* __restrict__ out)
{
  __shared__ bf16 RING[2][12288];    // per slot: A bytes [0,16384), B bytes [16384,24576)

  const int tid  = threadIdx.x;
  const int lane = tid & 63;
  const int wid  = tid >> 6;     // 0..3
  const int wm   = wid >> 1;     // 0..1 (64-row strip)
  const int wn   = wid & 1;      // 0..1 (32-col strip)
  const int lm   = lane & 15;
  const int lg   = lane >> 4;

  // per-XCD: XCD g owns m-blocks g*4..g*4+3, all 16 n-panels (A 2MB + B 4MB ~ L2)
  const int g   = blockIdx.x & 7;
  const int idx = blockIdx.x >> 3;           // 0..63
  const int m0  = (g * 4 + (idx >> 4)) * 128;
  const int n0  = (idx & 15) * 64;

  f32x4 acc[4][2];
#pragma unroll
  for (int i = 0; i < 4; ++i)
#pragma unroll
    for (int j = 0; j < 2; ++j) acc[i][j] = (f32x4)0.0f;

  const int rl = lane >> 3;
  const int cbb = (lane & 7) * 16;

  auto stage = [&](int kt, int slot) {       // 6 loads/thread
    const int k0 = kt * 64;
    char* Ab = (char*)&RING[slot][0];
    char* Bb = Ab + 16384;
#pragma unroll
    for (int r2 = 0; r2 < 4; ++r2) {         // A: 128 rows x 128B = 16 chunks
      int chunk = r2 * 4 + wid;
      int row   = chunk * 8 + rl;
      int cx    = cbb ^ ((row & 7) << 4);
      gload16(A + (size_t)(m0 + row) * QKVD + k0 + (cx >> 1), Ab + chunk * 1024);
    }
#pragma unroll
    for (int r2 = 0; r2 < 2; ++r2) {         // B: 64 rows x 128B = 8 chunks
      int chunk = r2 * 4 + wid;
      int row   = chunk * 8 + rl;
      int cx    = cbb ^ ((row & 7) << 4);
      gload16(Bw + (size_t)(n0 + row) * QKVD + k0 + (cx >> 1), Bb + chunk * 1024);
    }
  };

  auto rdA = [&](const char* Ab, int mf, int kk) -> bf16x8 {
    int row = wm * 64 + mf * 16 + lm;
    int cx  = (kk * 64 + lg * 16) ^ ((row & 7) << 4);
    return *(const bf16x8*)(Ab + row * 128 + cx);
  };
  auto rdB = [&](const char* Bb, int nf, int kk) -> bf16x8 {
    int row = wn * 32 + nf * 16 + lm;
    int cx  = (kk * 64 + lg * 16) ^ ((row & 7) << 4);
    return *(const bf16x8*)(Bb + row * 128 + cx);
  };

  stage(0, 0);

  int cur = 0;
  for (int t = 0; t < 32; ++t) {
    if (t < 31) {
      stage(t + 1, cur ^ 1);                 // issue BEFORE wait: stays in flight
      asm volatile("s_waitcnt vmcnt(6)" ::: "memory");   // tile t landed (FIFO)
    } else {
      asm volatile("s_waitcnt vmcnt(0)" ::: "memory");
    }
    __builtin_amdgcn_s_barrier();

    const char* Ab = (const char*)&RING[cur][0];
    const char* Bb = Ab + 16384;

    bf16x8 a[4], b[2];

    // ---- phase 0: kk0 ----
#pragma unroll
    for (int mf = 0; mf < 4; ++mf) a[mf] = rdA(Ab, mf, 0);
    b[0] = rdB(Bb, 0, 0); b[1] = rdB(Bb, 1, 0);
    __builtin_amdgcn_s_barrier();
    asm volatile("s_waitcnt lgkmcnt(0)" ::: "memory");
    __builtin_amdgcn_s_setprio(1);
#pragma unroll
    for (int mf = 0; mf < 4; ++mf) {
      acc[mf][0] = __builtin_amdgcn_mfma_f32_16x16x32_bf16(a[mf], b[0], acc[mf][0], 0, 0, 0);
      acc[mf][1] = __builtin_amdgcn_mfma_f32_16x16x32_bf16(a[mf], b[1], acc[mf][1], 0, 0, 0);
    }
    __builtin_amdgcn_s_setprio(0);
    __builtin_amdgcn_s_barrier();

    // ---- phase 1: kk1 ----
#pragma unroll
    for (int mf = 0; mf < 4; ++mf) a[mf] = rdA(Ab, mf, 1);
    b[0] = rdB(Bb, 0, 1); b[1] = rdB(Bb, 1, 1);
    __builtin_amdgcn_s_barrier();
    asm volatile("s_waitcnt lgkmcnt(0)" ::: "memory");
    __builtin_amdgcn_s_setprio(1);
#pragma unroll
    for (int mf = 0; mf < 4; ++mf) {
      acc[mf][0] = __builtin_amdgcn_mfma_f32_16x16x32_bf16(a[mf], b[0], acc[mf][0], 0, 0, 0);
      acc[mf][1] = __builtin_amdgcn_mfma_f32_16x16x32_bf16(a[mf], b[1], acc[mf][1], 0, 0, 0);
    }
    __builtin_amdgcn_s_setprio(0);
    __builtin_amdgcn_s_barrier();            // iter boundary: tile t consumed by all waves

    cur ^= 1;
  }

#pragma unroll
  for (int mf = 0; mf < 4; ++mf)
#pragma unroll
    for (int nf = 0; nf < 2; ++nf) {
      int row0 = m0 + wm * 64 + mf * 16 + lg * 4;
      int col  = n0 + wn * 32 + nf * 16 + lm;
      f32x4 cv = acc[mf][nf];
#pragma unroll
      for (int r = 0; r < 4; ++r)
        out[(size_t)(row0 + r) * DMOD + col] = cv[r];
    }
}

// ---------------- Flash attention: R10 structure + split QK accumulators (R16 best) ----
__global__ __launch_bounds__(256, 2) void flash_kernel(
    const bf16* __restrict__ Q, const bf16* __restrict__ Kg,
    const bf16* __restrict__ Vt, bf16* __restrict__ O)
{
  __shared__ bf16 KV[2][16384];      // per buf: K 64x128 (8192) | Vt 128x64 (8192) = 32KB

  const int tid  = threadIdx.x;
  const int lane = tid & 63;
  const int wid  = tid >> 6;
  const int l31  = lane & 31;
  const int lh   = lane >> 5;        // half: 0/1

  const int id  = blockIdx.x;                // 0..511
  const int c   = id & 255;
  const int s   = id >> 8;                   // CU slot 0/1
  const int bh  = (c & 7) * 4 + ((c >> 3) & 3);  // XCD (c&7) gets 4 bh
  const int k   = (c >> 5) & 7;              // pair index 0..7
  const int T   = s ? (15 - k) : k;          // tile 0..15; i and i+256 complement
  const int nu  = 2 * (T + 1);               // kv-units of 64 keys
  const int b   = bh >> 4;
  const int h   = bh & 15;
  const int rA  = T * 128 + wid * 32;        // wave's q-row base

  auto stage = [&](int j, int buf) {
    bf16* kb = &KV[buf][0];
    bf16* vb = &KV[buf][8192];
    const int rb0 = wid * 16;
#pragma unroll
    for (int i = 0; i < 4; ++i) {
      int r0 = rb0 + i * 4;
      int r  = r0 + (lane >> 4);
      int cc = ((lane & 15) * 16) ^ ((r & 15) << 4);    // full 16-slot swizzle (256B rows)
      gload16(Kg + ((size_t)(b * SEQ + j * 64 + r)) * QKVD + h * HDIM + (cc >> 1),
              kb + r0 * 128);
    }
    const int db0 = wid * 32;
#pragma unroll
    for (int i = 0; i < 4; ++i) {
      int d0 = db0 + i * 8;
      int d  = d0 + (lane >> 3);
      int cc = ((lane & 7) * 16) ^ ((d & 7) << 4);
      gload16(Vt + ((size_t)(bh * HDIM + d)) * SEQ + j * 64 + (cc >> 1),
              vb + d0 * 64);
    }
  };

  // Q fragments (pre-scaled by SCALE*log2e in GEMM)
  bf16x8 qfr[8];
  {
    const bf16* qb = Q + ((size_t)(b * SEQ + rA + l31)) * QKVD + h * HDIM + lh * 8;
#pragma unroll
    for (int st = 0; st < 8; ++st) qfr[st] = *reinterpret_cast<const bf16x8*>(qb + st * 16);
  }

  f32x16 o[4];
#pragma unroll
  for (int cc = 0; cc < 4; ++cc) o[cc] = (f32x16)0.0f;
  float mreg = -__builtin_inff();
  float lreg = 0.0f;

  stage(0, 0);
  __syncthreads();

  int cur = 0;
  for (int j = 0; j < nu; ++j) {
    if (j + 1 < nu) stage(j + 1, cur ^ 1);   // prefetch; drained by this unit's syncthreads

    const bool act = (j * 64 <= rA + 31);
    if (act) {
      const char* kbb = (const char*)&KV[cur][0];
      const char* vbb = kbb + 16384;

      // ---- S^T = K Q^T : 4 independent 4-deep chains ----
      f32x16 s0a = (f32x16)0.0f, s0b = (f32x16)0.0f;
      f32x16 s1a = (f32x16)0.0f, s1b = (f32x16)0.0f;
#pragma unroll
      for (int st = 0; st < 4; ++st) {
        const int r0 = l31, r1 = 32 + l31;
        bf16x8 kf0a = *(const bf16x8*)(kbb + r0 * 256 + ((lh * 16 + st * 32) ^ ((r0 & 15) << 4)));
        bf16x8 kf1a = *(const bf16x8*)(kbb + r1 * 256 + ((lh * 16 + st * 32) ^ ((r1 & 15) << 4)));
        bf16x8 kf0b = *(const bf16x8*)(kbb + r0 * 256 + ((lh * 16 + (st + 4) * 32) ^ ((r0 & 15) << 4)));
        bf16x8 kf1b = *(const bf16x8*)(kbb + r1 * 256 + ((lh * 16 + (st + 4) * 32) ^ ((r1 & 15) << 4)));
        s0a = __builtin_amdgcn_mfma_f32_32x32x16_bf16(kf0a, qfr[st],     s0a, 0, 0, 0);
        s1a = __builtin_amdgcn_mfma_f32_32x32x16_bf16(kf1a, qfr[st],     s1a, 0, 0, 0);
        s0b = __builtin_amdgcn_mfma_f32_32x32x16_bf16(kf0b, qfr[st + 4], s0b, 0, 0, 0);
        s1b = __builtin_amdgcn_mfma_f32_32x32x16_bf16(kf1b, qfr[st + 4], s1b, 0, 0, 0);
      }
      f32x16 s0 = s0a + s0b;
      f32x16 s1 = s1a + s1b;

      // ---- causal mask ----
      const bool full = (j * 64 + 63) <= rA;
      if (!full) {
        const int qr  = rA + l31;
        const int kb0 = j * 64 + 4 * lh;
#pragma unroll
        for (int r = 0; r < 16; ++r) {
          int key = kb0 + (r & 3) + 8 * (r >> 2);
          if (key > qr)      s0[r] = -1e30f;
          if (key + 32 > qr) s1[r] = -1e30f;
        }
      }

      // ---- in-lane row stats ----
      float mx = s0[0];
#pragma unroll
      for (int r = 1; r < 16; ++r) mx = fmaxf(mx, s0[r]);
#pragma unroll
      for (int r = 0; r < 16; ++r) mx = fmaxf(mx, s1[r]);
      mx = fmaxf(mx, __shfl_xor(mx, 32));

      float mn;
      if (__all(mx <= mreg + 8.0f)) {
        mn = mreg;                          // defer-max
      } else {
        mn = fmaxf(mreg, mx);
        float scl = exp2f(mreg - mn);
        mreg = mn;
        lreg *= scl;
#pragma unroll
        for (int r = 0; r < 16; ++r) {
          int row = (r & 3) + 8 * (r >> 2) + 4 * lh;
          float sr = __shfl(scl, row);
#pragma unroll
          for (int cc = 0; cc < 4; ++cc) o[cc][r] *= sr;
        }
      }

      // ---- exp + sum ----
      float p[32];
#pragma unroll
      for (int r = 0; r < 16; ++r) p[r]      = exp2f(s0[r] - mn);
#pragma unroll
      for (int r = 0; r < 16; ++r) p[16 + r] = exp2f(s1[r] - mn);
      float rs = 0.0f;
#pragma unroll
      for (int r = 0; r < 32; ++r) rs += p[r];
      rs += __shfl_xor(rs, 32);
      lreg += rs;

      // ---- pack P into PV A-fragments ----
      bf16x8 pa[4];
#pragma unroll
      for (int f = 0; f < 4; ++f) {
        const float* pp = p + f * 8;
        uint32_t w0 = pkbf(pp[0], pp[1]);
        uint32_t w1 = pkbf(pp[2], pp[3]);
        uint32_t w2 = pkbf(pp[4], pp[5]);
        uint32_t w3 = pkbf(pp[6], pp[7]);
        plswap(w0, w2);
        plswap(w1, w3);
        u32x4 w = {w0, w1, w2, w3};
        pa[f] = __builtin_bit_cast(bf16x8, w);
      }

      // ---- O += P V ----
#pragma unroll
      for (int cc = 0; cc < 4; ++cc) {
        const int d = cc * 32 + l31;
        const char* vrow = vbb + d * 128;
        const int dx = (d & 7) << 4;
#pragma unroll
        for (int f = 0; f < 4; ++f) {
          bf16x8 vf = *(const bf16x8*)(vrow + ((f * 32 + lh * 16) ^ dx));
          o[cc] = __builtin_amdgcn_mfma_f32_32x32x16_bf16(pa[f], vf, o[cc], 0, 0, 0);
        }
      }
    }

    __syncthreads();                         // drains prefetch + orders buffer reuse
    cur ^= 1;
  }

  // ---- epilogue: normalized O, direct write ----
  float linv = 1.0f / lreg;
#pragma unroll
  for (int cc = 0; cc < 4; ++cc)
#pragma unroll
    for (int r = 0; r < 16; ++r) {
      int row = (r & 3) + 8 * (r >> 2) + 4 * lh;
      float li = __shfl(linv, row);        // lane `row` owns q-row (rA+row)'s l
      O[((size_t)(b * SEQ + rA + row)) * QKVD + h * HDIM + cc * 32 + l31] =
          (bf16)(o[cc][r] * li);
    }
}

// ---------------- launch ----------------
extern "C" void kernel_launch(void* const* d_in, const int* in_sizes, int n_in,
                              void* d_out, int out_size, void* d_ws, size_t ws_size,
                              hipStream_t stream) {
  const float* x  = (const float*)d_in[0];
  const float* wq = (const float*)d_in[1];
  const float* wk = (const float*)d_in[2];
  const float* wv = (const float*)d_in[3];
  const float* wo = (const float*)d_in[4];
  float* out = (float*)d_out;

  bf16* xb  = (bf16*)d_ws;                 // 4096x1024
  bf16* wqb = xb  + (size_t)NTOK * DMOD;   // wq/wk/wv/wo contiguous bf16
  bf16* wob = wqb + (size_t)3 * QKVD * DMOD;
  bf16* Qb  = wob + (size_t)DMOD * QKVD;   // 4096x2048
  bf16* Kb  = Qb  + (size_t)NTOK * QKVD;
  bf16* Vtb = Kb  + (size_t)NTOK * QKVD;
  bf16* Ob  = Vtb + (size_t)NTOK * QKVD;

  // single cast launch: x + wq + wk + wv + wo -> bf16 (3145728 float4 units)
  cast_all<<<12288, 256, 0, stream>>>(x, wq, wk, wv, wo, xb);

  // fused QKV projection: [4096,1024] @ [6144,1024]^T, grid 768 (3 exact rounds)
  const float qs = 0.08838834764831845f * 1.4426950408889634f;  // SCALE * log2(e)
  qkv_gemm_kernel<<<768, 512, 0, stream>>>(xb, wqb, Qb, Kb, Vtb, qs);

  // attention: 512 blocks (tile-per-block, complementary CU pairing), direct O
  flash_kernel<<<512, 256, 0, stream>>>(Qb, Kb, Vtb, Ob);

  // output projection: [4096,2048] @ [1024,2048]^T -> [4096,1024] fp32, grid 512 (2/CU)
  proj_kernel<<<512, 256, 0, stream>>>(Ob, wob, out);
}